// Round 8
// baseline (265.996 us; speedup 1.0000x reference)
//
#include <hip/hip_runtime.h>
#include <hip/hip_bf16.h>
#include <hip/hip_fp16.h>

// Problem constants
#define N_NODES 50000
#define N_EDGES 500000
#define IN_CH   128
#define D       256   // HEADS * OUT_CH
#define UDIM    512   // HEADS * 128 (u and y width)
#define OUT_CH  64
#define HEADS   4
#define NC      49    // scan chunks of 1024: ceil(50000/1024)
#define PCAP    448   // LDS payload staging capacity per block (span ~ Poisson(160))
#define DEPTH   4     // async x-gather ring depth (per wave)

// K1 grid sections
#define NB_X16  6250  // 50000*128/4/256
#define NB_HIST 1954  // ceil(500000/256)
#define NB_MB   256   // 512 M-rows, 2 per block
#define NB_ZB   128   // 512 Zc-rows, 4 per block
// K4 grid sections (gemm_u || scatter, proportionally interleaved)
#define NB_GEMM4 391  // 391 row-blocks, each loops over 4 column-groups
#define NB_SCAT 1954  // ceil(500000/256)
#define NB_K4   (NB_GEMM4 + NB_SCAT)

typedef _Float16 half8 __attribute__((ext_vector_type(8)));   // 4 VGPRs (MFMA A/B)
typedef _Float16 half2_t __attribute__((ext_vector_type(2))); // 1 VGPR packed
typedef float   floatx4 __attribute__((ext_vector_type(4)));  // 4 VGPRs (MFMA C/D)

typedef __attribute__((address_space(1))) const void as1_void;
typedef __attribute__((address_space(3))) void as3_void;

__device__ __forceinline__ void gll16(const void* g, void* l) {
    __builtin_amdgcn_global_load_lds((as1_void*)g, (as3_void*)l, 16, 0, 0);
}

// DPP quad-perm butterfly adds (4 q-lanes of one head form one aligned quad)
__device__ __forceinline__ float dpp_xor1(float x) {
    return __int_as_float(__builtin_amdgcn_mov_dpp(__float_as_int(x), 0xB1, 0xf, 0xf, true));
}
__device__ __forceinline__ float dpp_xor2(float x) {
    return __int_as_float(__builtin_amdgcn_mov_dpp(__float_as_int(x), 0x4E, 0xf, 0xf, true));
}

// ---------------------------------------------------------------------------
// K1 (fused): x16 convert | tgt histogram | M16t build | Zc16t build
// ---------------------------------------------------------------------------
__global__ __launch_bounds__(256) void k1_prep_kernel(const float* __restrict__ x,
                                                      __half* __restrict__ x16,
                                                      const int* __restrict__ ei,
                                                      int* __restrict__ cnt,
                                                      double* __restrict__ S,
                                                      const float* __restrict__ Wq,
                                                      const float* __restrict__ Wk,
                                                      const float* __restrict__ Wv,
                                                      const float* __restrict__ Wout,
                                                      __half* __restrict__ M16t,
                                                      __half* __restrict__ Zc16t) {
    __shared__ float sbuf[4][64];
    const int b = blockIdx.x, tid = threadIdx.x;
    if (b < NB_X16) {
        int i = b * 256 + tid;
        if (i < HEADS) S[i] = 0.0;
        int k = i * 4;
        if (k < N_NODES * IN_CH) {
            float4 v = *(const float4*)(x + k);
            union { __half2 h[2]; uint2 u; } pk;
            pk.h[0] = __floats2half2_rn(v.x, v.y);
            pk.h[1] = __floats2half2_rn(v.z, v.w);
            *(uint2*)(x16 + k) = pk.u;
        }
    } else if (b < NB_X16 + NB_HIST) {
        int e = (b - NB_X16) * 256 + tid;
        if (e < N_EDGES) atomicAdd(&cnt[ei[N_EDGES + e]], 1);
    } else if (b < NB_X16 + NB_HIST + NB_MB) {
        const int r = (b - NB_X16 - NB_HIST) * 2 + (tid >> 7);  // M-row 0..511
        const int i = tid & 127;
        const int h = r >> 7, j = r & 127;
        float* buf = sbuf[tid >> 7];
        if (i < 64) buf[i] = Wk[(size_t)j * D + h * 64 + i];
        __syncthreads();
        const float4* qr = (const float4*)(Wq + (size_t)i * D + h * 64);
        float s = 0.f;
        #pragma unroll
        for (int c4 = 0; c4 < 16; ++c4) {
            float4 q = qr[c4];
            s += q.x * buf[c4 * 4] + q.y * buf[c4 * 4 + 1]
               + q.z * buf[c4 * 4 + 2] + q.w * buf[c4 * 4 + 3];
        }
        M16t[(size_t)r * IN_CH + i] = __float2half(s);
    } else {
        const int r = (b - NB_X16 - NB_HIST - NB_MB) * 4 + (tid >> 6); // Zc-row
        const int c = tid & 63;
        const int h = r >> 7, i = r & 127;
        float* buf = sbuf[tid >> 6];
        buf[c] = Wv[(size_t)i * D + h * 64 + c];
        __syncthreads();
        float s = 0.f;
        #pragma unroll 8
        for (int j = 0; j < 64; ++j)
            s += buf[j] * Wout[(size_t)(h * 64 + j) * OUT_CH + c];
        Zc16t[(size_t)c * UDIM + r] = __float2half(s);
    }
}

// ---------------------------------------------------------------------------
// K2: scan_reduce — per-1024-chunk sums of cnt into csum (49 blocks)
// ---------------------------------------------------------------------------
__global__ __launch_bounds__(256) void k2_scan_reduce_kernel(const int* __restrict__ cnt,
                                                             int* __restrict__ csum) {
    const int b = blockIdx.x, tid = threadIdx.x;
    const int lane = tid & 63, wid = tid >> 6;
    int s = 0;
    int idx0 = b * 1024 + tid * 4;
    #pragma unroll
    for (int i = 0; i < 4; ++i) {
        int idx = idx0 + i;
        if (idx < N_NODES) s += cnt[idx];
    }
    #pragma unroll
    for (int m = 1; m < 64; m <<= 1) s += __shfl_xor(s, m, 64);
    __shared__ int w4[4];
    if (lane == 0) w4[wid] = s;
    __syncthreads();
    if (tid == 0) csum[b] = w4[0] + w4[1] + w4[2] + w4[3];
}

// ---------------------------------------------------------------------------
// K3: scan_chunks with inlined 49-element top-scan
// ---------------------------------------------------------------------------
__global__ __launch_bounds__(256) void k3_scan_chunks_kernel(int* __restrict__ cnt,
                                                             const int* __restrict__ csum,
                                                             int* __restrict__ rp) {
    __shared__ int stop[64];
    __shared__ int wsum[4];
    const int b = blockIdx.x, tid = threadIdx.x;
    const int lane = tid & 63, wid = tid >> 6;
    if (tid < 64) stop[tid] = (tid < NC) ? csum[tid] : 0;
    __syncthreads();
    int base = 0;
    for (int w = 0; w < b; ++w) base += stop[w];
    int v[4];
    const int idx0 = b * 1024 + tid * 4;
    #pragma unroll
    for (int i = 0; i < 4; ++i) {
        int idx = idx0 + i;
        v[i] = (idx < N_NODES) ? cnt[idx] : 0;
    }
    int tsum = v[0] + v[1] + v[2] + v[3];
    int x = tsum;
    #pragma unroll
    for (int d = 1; d < 64; d <<= 1) {
        int y = __shfl_up(x, d, 64);
        if (lane >= d) x += y;
    }
    if (lane == 63) wsum[wid] = x;
    __syncthreads();
    int woff = 0;
    for (int w = 0; w < wid; ++w) woff += wsum[w];
    int excl = base + woff + x - tsum;
    #pragma unroll
    for (int i = 0; i < 4; ++i) {
        int idx = idx0 + i;
        if (idx < N_NODES) { rp[idx] = excl; cnt[idx] = excl; }
        excl += v[i];
    }
}

// ---------------------------------------------------------------------------
// K4 (fused; gemm/scatter blocks proportionally interleaved):
//   gemm blocks (391): GEMM1 u16 = x16 @ M16t^T; one 128-ROW block loops over
//     all 4 column-groups with A fragments held in registers -> x16 read ONCE
//     (12.8MB vs 51MB). Bm staged per column-group (validated sequence).
//   scat blocks (1954): scatter edges -> payload {src, w} (CSR by tgt)
// ---------------------------------------------------------------------------
__global__ __launch_bounds__(256) void k4_gemmu_scatter_kernel(const __half* __restrict__ x16,
                                                               const __half* __restrict__ M16t,
                                                               __half* __restrict__ u16,
                                                               const int* __restrict__ ei,
                                                               const float* __restrict__ ew,
                                                               int* __restrict__ cnt,
                                                               int2* __restrict__ payload) {
    __shared__ __half Bm[128][136];   // 34,816 B; B-tile, then C staging
    const int tid = threadIdx.x;
    const int b = blockIdx.x;
    // proportional striping: exact NB_GEMM4 gemm slots, NB_SCAT scatter slots
    const int glo = (int)(((long long)b * NB_GEMM4) / NB_K4);
    const int ghi = (int)(((long long)(b + 1) * NB_GEMM4) / NB_K4);
    if (ghi == glo) {
        // ---- scatter (id = b - glo) ----
        int e = (b - glo) * 256 + tid;
        if (e < N_EDGES) {
            int s = ei[e], t = ei[N_EDGES + e];
            int pos = atomicAdd(&cnt[t], 1);
            payload[pos] = make_int2(s, __float_as_int(ew[e]));
        }
        return;
    }
    // ---- GEMM1 (row-block id = glo) ----
    const int m0 = glo * 128;
    const int w = tid >> 6, lane = tid & 63;
    const int mrow = lane & 15, quad = lane >> 4;

    // A fragments: direct from x16, loaded ONCE for all 4 column-groups
    half8 a[2][4];
    #pragma unroll
    for (int mt = 0; mt < 2; ++mt) {
        int row = min(m0 + w * 32 + mt * 16 + mrow, N_NODES - 1); // pad rows read 49999; never stored
        const __half* ab = x16 + (size_t)row * IN_CH + quad * 8;
        #pragma unroll
        for (int ks = 0; ks < 4; ++ks) a[mt][ks] = *(const half8*)(ab + ks * 32);
    }

    for (int cb = 0; cb < 4; ++cb) {
        const int colbase = cb * 128;
        {   // stage B-tile for this column-group
            const int r = tid >> 1, part = tid & 1;   // 64 halves = 8 uint4/thread
            const uint4* sb = (const uint4*)(M16t + (size_t)(colbase + r) * IN_CH + part * 64);
            uint4* db = (uint4*)&Bm[r][part * 64];
            #pragma unroll
            for (int q = 0; q < 8; ++q) db[q] = sb[q];
        }
        __syncthreads();

        floatx4 acc[2][8];
        #pragma unroll
        for (int mt = 0; mt < 2; ++mt)
            #pragma unroll
            for (int nt = 0; nt < 8; ++nt)
                acc[mt][nt] = (floatx4){0.f, 0.f, 0.f, 0.f};

        #pragma unroll
        for (int nt = 0; nt < 8; ++nt) {
            #pragma unroll
            for (int ks = 0; ks < 4; ++ks) {
                half8 bfr = *(const half8*)&Bm[nt * 16 + mrow][ks * 32 + quad * 8];
                acc[0][nt] = __builtin_amdgcn_mfma_f32_16x16x32_f16(a[0][ks], bfr, acc[0][nt], 0, 0, 0);
                acc[1][nt] = __builtin_amdgcn_mfma_f32_16x16x32_f16(a[1][ks], bfr, acc[1][nt], 0, 0, 0);
            }
        }
        __syncthreads();   // all waves done reading Bm before overwrite
        #pragma unroll
        for (int mt = 0; mt < 2; ++mt)
            #pragma unroll
            for (int nt = 0; nt < 8; ++nt)
                #pragma unroll
                for (int r = 0; r < 4; ++r)
                    Bm[w * 32 + mt * 16 + quad * 4 + r][nt * 16 + mrow] = __float2half(acc[mt][nt][r]);
        __syncthreads();
        {
            const int r = tid >> 1, part = tid & 1;
            if (m0 + r < N_NODES) {
                const uint4* s4 = (const uint4*)&Bm[r][part * 64];
                uint4* d4 = (uint4*)(u16 + (size_t)(m0 + r) * UDIM + colbase + part * 64);
                #pragma unroll
                for (int q = 0; q < 8; ++q) d4[q] = s4[q];
            }
        }
        __syncthreads();   // stores done before next column-group restages Bm
    }
}

// ---------------------------------------------------------------------------
// Fused edge kernel v8 (round-5 validated): async global_load_lds x-gather
// ring (DEPTH=4/wave, counted vmcnt(3), no in-loop barriers), 4 parallel
// fdot2 accumulators, DPP quad_perm reduction, PCAP=448.
// ---------------------------------------------------------------------------
__global__ __launch_bounds__(256) void edge_fused_kernel(const __half* __restrict__ u16,
                                                         const __half* __restrict__ x16,
                                                         const int* __restrict__ rp,
                                                         const int* __restrict__ cnt,
                                                         const int2* __restrict__ payload,
                                                         const float* __restrict__ We,
                                                         __half* __restrict__ y16,
                                                         double* __restrict__ S) {
    __shared__ __half xring[4][DEPTH][512];   // [wave][slot][4 node-rows x 256B] = 16KB
    __shared__ int2 pbuf[PCAP];               // 3.5KB
    __shared__ float sblk[4];
    const int tid = threadIdx.x;
    const int nodebase = blockIdx.x * 16;

    const int span0 = rp[nodebase];
    const int span1 = cnt[nodebase + 15];
    const int span  = span1 - span0;
    const int span_len = min(span, PCAP);
    for (int i = tid; i < span_len; i += 256) pbuf[i] = payload[span0 + i];
    if (tid < 4) sblk[tid] = 0.f;
    __syncthreads();

    const int w = tid >> 6, lane = tid & 63;
    const int g = lane >> 4;         // node-group within wave (0..3)
    const int l16 = lane & 15;
    const int h = l16 >> 2;          // head 0..3
    const int q = l16 & 3;           // channel quarter 0..3
    const int node = nodebase + (tid >> 4);
    const float wev = We[h];

    uint4 ur4[4];
    {
        const uint4* ub = (const uint4*)(u16 + (size_t)node * UDIM + h * 128 + q * 32);
        ur4[0] = ub[0]; ur4[1] = ub[1]; ur4[2] = ub[2]; ur4[3] = ub[3];
    }
    const half2_t* uh = (const half2_t*)ur4;    // 16 half2

    half2_t yacc[16];
    #pragma unroll
    for (int t = 0; t < 16; ++t) yacc[t] = (half2_t){(_Float16)0.f, (_Float16)0.f};

    float sacc = 0.f;
    const int start = rp[node];
    const int end = cnt[node];
    const int ng = end - start;

    if (span <= PCAP) {
        // ================= fast path: async ring =================
        int nmax = ng;
        nmax = max(nmax, __shfl_xor(nmax, 16, 64));
        nmax = max(nmax, __shfl_xor(nmax, 32, 64));
        if (nmax > 0) {
            // swizzled source chunk for this lane: chunk index = l16 ^ g (16B chunks)
            const int chunk_off = (l16 ^ g) * 8;   // in halves
            auto src_of = [&](int t) -> const __half* {
                int idx = min(start + t, end - 1);
                idx = max(idx, span0);             // ng==0 lanes clamp into valid span
                int s = pbuf[idx - span0].x;
                return x16 + (size_t)s * IN_CH + chunk_off;
            };
            #pragma unroll
            for (int s = 0; s < DEPTH; ++s)
                gll16(src_of(s), &xring[w][s][0]);

            for (int t = 0; t < nmax; ++t) {
                const int slot = t & (DEPTH - 1);
                asm volatile("s_waitcnt vmcnt(3)" ::: "memory");   // DEPTH-1
                __builtin_amdgcn_sched_barrier(0);
                // read this lane's 64B quarter (chunks q*4..q*4+3, de-swizzled)
                const uint4* rb = (const uint4*)&xring[w][slot][g * 128 + q * 32];
                uint4 xr0 = rb[0 ^ g];
                uint4 xr1 = rb[1 ^ g];
                uint4 xr2 = rb[2 ^ g];
                uint4 xr3 = rb[3 ^ g];
                asm volatile("s_waitcnt lgkmcnt(0)" ::: "memory"); // reads done before overwrite
                __builtin_amdgcn_sched_barrier(0);
                gll16(src_of(t + DEPTH), &xring[w][slot][0]);      // reissue (unconditional!)

                int2 pl;
                {
                    int idx = min(start + t, end - 1);
                    idx = max(idx, span0);
                    pl = pbuf[idx - span0];
                }
                uint4 xr[4] = {xr0, xr1, xr2, xr3};
                const half2_t* xh = (const half2_t*)xr;
                float d0 = 0.f, d1 = 0.f, d2 = 0.f, d3 = 0.f;
                #pragma unroll
                for (int tt = 0; tt < 4; ++tt) {
                    d0 = __builtin_amdgcn_fdot2(uh[tt],      xh[tt],      d0, false);
                    d1 = __builtin_amdgcn_fdot2(uh[tt + 4],  xh[tt + 4],  d1, false);
                    d2 = __builtin_amdgcn_fdot2(uh[tt + 8],  xh[tt + 8],  d2, false);
                    d3 = __builtin_amdgcn_fdot2(uh[tt + 12], xh[tt + 12], d3, false);
                }
                float dot = (d0 + d1) + (d2 + d3);
                dot += dpp_xor1(dot);
                dot += dpp_xor2(dot);            // sum over the 4 q-lanes (one aligned quad)
                float l = dot * 0.125f + __int_as_float(pl.y) * wev;
                l = fmaxf(l, 0.2f * l);          // leaky_relu(0.2)
                float p = __expf(l);
                if (t < ng) {
                    if (q == 0) sacc += p;
                    half2_t p2 = (half2_t){(_Float16)p, (_Float16)p};
                    #pragma unroll
                    for (int tt = 0; tt < 16; ++tt)
                        yacc[tt] = p2 * xh[tt] + yacc[tt];   // v_pk_fma_f16
                }
            }
        }
    } else {
        // ================= slow path (span > PCAP, ~never) =================
        auto getpl = [&](int e) -> int2 {
            int idx = e - span0;
            return (idx < PCAP) ? pbuf[idx] : payload[e];
        };
        int2 pl = make_int2(0, 0);
        uint4 xr[4];
        if (start < end) {
            pl = getpl(start);
            const uint4* xb = (const uint4*)(x16 + (size_t)pl.x * IN_CH + q * 32);
            xr[0] = xb[0]; xr[1] = xb[1]; xr[2] = xb[2]; xr[3] = xb[3];
        }
        for (int e = start; e < end; ++e) {
            int2 pln = pl;
            uint4 xrn[4] = {xr[0], xr[1], xr[2], xr[3]};
            if (e + 1 < end) {
                pln = getpl(e + 1);
                const uint4* xb = (const uint4*)(x16 + (size_t)pln.x * IN_CH + q * 32);
                xrn[0] = xb[0]; xrn[1] = xb[1]; xrn[2] = xb[2]; xrn[3] = xb[3];
            }
            const half2_t* xh = (const half2_t*)xr;
            float dot = 0.f;
            #pragma unroll
            for (int t = 0; t < 16; ++t)
                dot = __builtin_amdgcn_fdot2(uh[t], xh[t], dot, false);
            dot += __shfl_xor(dot, 1, 16);
            dot += __shfl_xor(dot, 2, 16);
            float l = dot * 0.125f + __int_as_float(pl.y) * wev;
            l = fmaxf(l, 0.2f * l);
            float p = __expf(l);
            if (q == 0) sacc += p;
            half2_t p2 = (half2_t){(_Float16)p, (_Float16)p};
            #pragma unroll
            for (int t = 0; t < 16; ++t)
                yacc[t] = p2 * xh[t] + yacc[t];
            pl = pln;
            xr[0] = xrn[0]; xr[1] = xrn[1]; xr[2] = xrn[2]; xr[3] = xrn[3];
        }
    }
    {
        uint4* yo = (uint4*)(y16 + (size_t)node * UDIM + h * 128 + q * 32);
        const uint4* ys = (const uint4*)yacc;
        yo[0] = ys[0]; yo[1] = ys[1]; yo[2] = ys[2]; yo[3] = ys[3];
    }
    __syncthreads();
    if (q == 0) atomicAdd(&sblk[h], sacc);
    __syncthreads();
    if (tid < 4) atomicAdd(&S[tid], (double)sblk[tid]);
}

// ---------------------------------------------------------------------------
// GEMM2 (MFMA, round-5 validated LDS version): out = sum_h invs[h] *
// (y16_h @ Zc16t_h^T) + b_out. Bz staged in LDS (reused by 4 waves).
// ---------------------------------------------------------------------------
__global__ __launch_bounds__(256) void gemm_out_mfma_kernel(const __half* __restrict__ y16,
                                                            const __half* __restrict__ Zc16t,
                                                            const double* __restrict__ S,
                                                            const float* __restrict__ b_out,
                                                            float* __restrict__ out) {
    __shared__ __half Ay[128][136];
    __shared__ __half Bz[64][136];
    __shared__ float invs_s[4];
    const int m0 = blockIdx.x * 128;
    const int tid = threadIdx.x;
    if (tid < 4) invs_s[tid] = (float)(1.0 / S[tid]);

    const int w = tid >> 6, lane = tid & 63;
    const int mrow = lane & 15, quad = lane >> 4;

    floatx4 result[2][4];
    #pragma unroll
    for (int mt = 0; mt < 2; ++mt)
        #pragma unroll
        for (int nt = 0; nt < 4; ++nt)
            result[mt][nt] = (floatx4){0.f, 0.f, 0.f, 0.f};

    for (int h = 0; h < HEADS; ++h) {
        {
            const int r = tid >> 1, part = tid & 1;   // 8 uint4/thread
            uint4 va[8];
            if (m0 + r < N_NODES) {
                const uint4* src = (const uint4*)(y16 + (size_t)(m0 + r) * UDIM + h * 128 + part * 64);
                #pragma unroll
                for (int qq = 0; qq < 8; ++qq) va[qq] = src[qq];
            } else {
                #pragma unroll
                for (int qq = 0; qq < 8; ++qq) va[qq] = make_uint4(0u, 0u, 0u, 0u);
            }
            uint4* da = (uint4*)&Ay[r][part * 64];
            #pragma unroll
            for (int qq = 0; qq < 8; ++qq) da[qq] = va[qq];
        }
        {
            const int r = tid >> 2, part = tid & 3;   // 4 uint4/thread
            const uint4* sb = (const uint4*)(Zc16t + (size_t)r * UDIM + h * 128 + part * 32);
            uint4* db = (uint4*)&Bz[r][part * 32];
            #pragma unroll
            for (int qq = 0; qq < 4; ++qq) db[qq] = sb[qq];
        }
        __syncthreads();

        half8 a[2][4];
        #pragma unroll
        for (int mt = 0; mt < 2; ++mt)
            #pragma unroll
            for (int ks = 0; ks < 4; ++ks)
                a[mt][ks] = *(const half8*)&Ay[w * 32 + mt * 16 + mrow][ks * 32 + quad * 8];

        floatx4 acc[2][4];
        #pragma unroll
        for (int mt = 0; mt < 2; ++mt)
            #pragma unroll
            for (int nt = 0; nt < 4; ++nt)
                acc[mt][nt] = (floatx4){0.f, 0.f, 0.f, 0.f};

        #pragma unroll
        for (int nt = 0; nt < 4; ++nt) {
            #pragma unroll
            for (int ks = 0; ks < 4; ++ks) {
                half8 bfr = *(const half8*)&Bz[nt * 16 + mrow][ks * 32 + quad * 8];
                acc[0][nt] = __builtin_amdgcn_mfma_f32_16x16x32_f16(a[0][ks], bfr, acc[0][nt], 0, 0, 0);
                acc[1][nt] = __builtin_amdgcn_mfma_f32_16x16x32_f16(a[1][ks], bfr, acc[1][nt], 0, 0, 0);
            }
        }
        const float inv = invs_s[h];
        #pragma unroll
        for (int mt = 0; mt < 2; ++mt)
            #pragma unroll
            for (int nt = 0; nt < 4; ++nt) {
                result[mt][nt][0] += inv * acc[mt][nt][0];
                result[mt][nt][1] += inv * acc[mt][nt][1];
                result[mt][nt][2] += inv * acc[mt][nt][2];
                result[mt][nt][3] += inv * acc[mt][nt][3];
            }
        __syncthreads();
    }
    float bcol[4];
    #pragma unroll
    for (int nt = 0; nt < 4; ++nt) bcol[nt] = b_out[nt * 16 + mrow];
    #pragma unroll
    for (int mt = 0; mt < 2; ++mt) {
        #pragma unroll
        for (int r = 0; r < 4; ++r) {
            int row = m0 + w * 32 + mt * 16 + quad * 4 + r;
            if (row < N_NODES) {
                float* dst = out + (size_t)row * OUT_CH;
                #pragma unroll
                for (int nt = 0; nt < 4; ++nt)
                    dst[nt * 16 + mrow] = result[mt][nt][r] + bcol[nt];
            }
        }
    }
}

// ---------------------------------------------------------------------------
// Launch
// ---------------------------------------------------------------------------
extern "C" void kernel_launch(void* const* d_in, const int* in_sizes, int n_in,
                              void* d_out, int out_size, void* d_ws, size_t ws_size,
                              hipStream_t stream) {
    const float* x     = (const float*)d_in[0];
    const int*   ei    = (const int*)d_in[1];   // [2, E] int32
    const float* ew    = (const float*)d_in[2];
    const float* Wq    = (const float*)d_in[3];
    const float* Wk    = (const float*)d_in[4];
    const float* Wv    = (const float*)d_in[5];
    const float* We    = (const float*)d_in[6];
    const float* Wout  = (const float*)d_in[7];
    const float* b_out = (const float*)d_in[8];
    float* out = (float*)d_out;

    // workspace layout (~120 MB)
    __half* u16   = (__half*)d_ws;                          // 50000*512*2 = 51.2 MB
    __half* y16   = u16 + (size_t)N_NODES * UDIM;           // 51.2 MB
    __half* x16   = y16 + (size_t)N_NODES * UDIM;           // 12.8 MB
    double* S     = (double*)(x16 + (size_t)N_NODES * IN_CH);  // 4 doubles
    __half* M16t  = (__half*)(S + HEADS);                   // 512*128*2 = 128 KB
    __half* Zc16t = M16t + UDIM * IN_CH;                    // 64*512*2 = 64 KB
    int*    rp    = (int*)(Zc16t + OUT_CH * UDIM);          // 50000
    int*    cnt   = rp + N_NODES;                           // 50000
    int*    csum  = cnt + N_NODES;                          // 64
    int2*   payload = (int2*)(csum + 64);                   // 500000*8 = 4 MB

    hipMemsetAsync(cnt, 0, N_NODES * sizeof(int), stream);
    k1_prep_kernel<<<NB_X16 + NB_HIST + NB_MB + NB_ZB, 256, 0, stream>>>(
        x, x16, ei, cnt, S, Wq, Wk, Wv, Wout, M16t, Zc16t);
    k2_scan_reduce_kernel<<<NC, 256, 0, stream>>>(cnt, csum);
    k3_scan_chunks_kernel<<<NC, 256, 0, stream>>>(cnt, csum, rp);
    k4_gemmu_scatter_kernel<<<NB_K4, 256, 0, stream>>>(
        x16, M16t, u16, ei, ew, cnt, payload);
    edge_fused_kernel<<<N_NODES / 16, 256, 0, stream>>>(u16, x16, rp, cnt, payload, We, y16, S);
    gemm_out_mfma_kernel<<<(N_NODES + 127) / 128, 256, 0, stream>>>(y16, Zc16t, S, b_out, out);
}

// Round 9
// 237.805 us; speedup vs baseline: 1.1185x; 1.1185x over previous
//
#include <hip/hip_runtime.h>
#include <hip/hip_bf16.h>
#include <hip/hip_fp16.h>

// Problem constants
#define N_NODES 50000
#define N_EDGES 500000
#define IN_CH   128
#define D       256   // HEADS * OUT_CH
#define UDIM    512   // HEADS * 128 (u and y width)
#define OUT_CH  64
#define HEADS   4
#define NC      49    // scan chunks of 1024: ceil(50000/1024)
#define PCAP    448   // LDS payload staging capacity per block (span ~ Poisson(160))
#define DEPTH   4     // async x-gather ring depth (per wave)

// K1 grid sections
#define NB_X16  6250  // 50000*128/4/256
#define NB_HIST 1954  // ceil(500000/256)
#define NB_MB   256   // 512 M-rows, 2 per block
#define NB_ZB   128   // 512 Zc-rows, 4 per block
// K4 grid sections (gemm_u || scatter, proportionally interleaved) — round-5 validated
#define NB_GEMM 1564  // 391 * 4
#define NB_SCAT 1954  // ceil(500000/256)
#define NB_K4   (NB_GEMM + NB_SCAT)

typedef _Float16 half8 __attribute__((ext_vector_type(8)));   // 4 VGPRs (MFMA A/B)
typedef _Float16 half2_t __attribute__((ext_vector_type(2))); // 1 VGPR packed
typedef float   floatx4 __attribute__((ext_vector_type(4)));  // 4 VGPRs (MFMA C/D)

typedef __attribute__((address_space(1))) const void as1_void;
typedef __attribute__((address_space(3))) void as3_void;

__device__ __forceinline__ void gll16(const void* g, void* l) {
    __builtin_amdgcn_global_load_lds((as1_void*)g, (as3_void*)l, 16, 0, 0);
}

// DPP quad-perm butterfly adds (4 q-lanes of one head form one aligned quad)
__device__ __forceinline__ float dpp_xor1(float x) {
    return __int_as_float(__builtin_amdgcn_mov_dpp(__float_as_int(x), 0xB1, 0xf, 0xf, true));
}
__device__ __forceinline__ float dpp_xor2(float x) {
    return __int_as_float(__builtin_amdgcn_mov_dpp(__float_as_int(x), 0x4E, 0xf, 0xf, true));
}

// ---------------------------------------------------------------------------
// K1 (fused): x16 convert | tgt histogram | M16t build | Zc16t build
// ---------------------------------------------------------------------------
__global__ __launch_bounds__(256) void k1_prep_kernel(const float* __restrict__ x,
                                                      __half* __restrict__ x16,
                                                      const int* __restrict__ ei,
                                                      int* __restrict__ cnt,
                                                      double* __restrict__ S,
                                                      const float* __restrict__ Wq,
                                                      const float* __restrict__ Wk,
                                                      const float* __restrict__ Wv,
                                                      const float* __restrict__ Wout,
                                                      __half* __restrict__ M16t,
                                                      __half* __restrict__ Zc16t) {
    __shared__ float sbuf[4][64];
    const int b = blockIdx.x, tid = threadIdx.x;
    if (b < NB_X16) {
        int i = b * 256 + tid;
        if (i < HEADS) S[i] = 0.0;
        int k = i * 4;
        if (k < N_NODES * IN_CH) {
            float4 v = *(const float4*)(x + k);
            union { __half2 h[2]; uint2 u; } pk;
            pk.h[0] = __floats2half2_rn(v.x, v.y);
            pk.h[1] = __floats2half2_rn(v.z, v.w);
            *(uint2*)(x16 + k) = pk.u;
        }
    } else if (b < NB_X16 + NB_HIST) {
        int e = (b - NB_X16) * 256 + tid;
        if (e < N_EDGES) atomicAdd(&cnt[ei[N_EDGES + e]], 1);
    } else if (b < NB_X16 + NB_HIST + NB_MB) {
        const int r = (b - NB_X16 - NB_HIST) * 2 + (tid >> 7);  // M-row 0..511
        const int i = tid & 127;
        const int h = r >> 7, j = r & 127;
        float* buf = sbuf[tid >> 7];
        if (i < 64) buf[i] = Wk[(size_t)j * D + h * 64 + i];
        __syncthreads();
        const float4* qr = (const float4*)(Wq + (size_t)i * D + h * 64);
        float s = 0.f;
        #pragma unroll
        for (int c4 = 0; c4 < 16; ++c4) {
            float4 q = qr[c4];
            s += q.x * buf[c4 * 4] + q.y * buf[c4 * 4 + 1]
               + q.z * buf[c4 * 4 + 2] + q.w * buf[c4 * 4 + 3];
        }
        M16t[(size_t)r * IN_CH + i] = __float2half(s);
    } else {
        const int r = (b - NB_X16 - NB_HIST - NB_MB) * 4 + (tid >> 6); // Zc-row
        const int c = tid & 63;
        const int h = r >> 7, i = r & 127;
        float* buf = sbuf[tid >> 6];
        buf[c] = Wv[(size_t)i * D + h * 64 + c];
        __syncthreads();
        float s = 0.f;
        #pragma unroll 8
        for (int j = 0; j < 64; ++j)
            s += buf[j] * Wout[(size_t)(h * 64 + j) * OUT_CH + c];
        Zc16t[(size_t)c * UDIM + r] = __float2half(s);
    }
}

// ---------------------------------------------------------------------------
// K2: scan_reduce — per-1024-chunk sums of cnt into csum (49 blocks)
// ---------------------------------------------------------------------------
__global__ __launch_bounds__(256) void k2_scan_reduce_kernel(const int* __restrict__ cnt,
                                                             int* __restrict__ csum) {
    const int b = blockIdx.x, tid = threadIdx.x;
    const int lane = tid & 63, wid = tid >> 6;
    int s = 0;
    int idx0 = b * 1024 + tid * 4;
    #pragma unroll
    for (int i = 0; i < 4; ++i) {
        int idx = idx0 + i;
        if (idx < N_NODES) s += cnt[idx];
    }
    #pragma unroll
    for (int m = 1; m < 64; m <<= 1) s += __shfl_xor(s, m, 64);
    __shared__ int w4[4];
    if (lane == 0) w4[wid] = s;
    __syncthreads();
    if (tid == 0) csum[b] = w4[0] + w4[1] + w4[2] + w4[3];
}

// ---------------------------------------------------------------------------
// K3: scan_chunks with inlined 49-element top-scan
// ---------------------------------------------------------------------------
__global__ __launch_bounds__(256) void k3_scan_chunks_kernel(int* __restrict__ cnt,
                                                             const int* __restrict__ csum,
                                                             int* __restrict__ rp) {
    __shared__ int stop[64];
    __shared__ int wsum[4];
    const int b = blockIdx.x, tid = threadIdx.x;
    const int lane = tid & 63, wid = tid >> 6;
    if (tid < 64) stop[tid] = (tid < NC) ? csum[tid] : 0;
    __syncthreads();
    int base = 0;
    for (int w = 0; w < b; ++w) base += stop[w];
    int v[4];
    const int idx0 = b * 1024 + tid * 4;
    #pragma unroll
    for (int i = 0; i < 4; ++i) {
        int idx = idx0 + i;
        v[i] = (idx < N_NODES) ? cnt[idx] : 0;
    }
    int tsum = v[0] + v[1] + v[2] + v[3];
    int x = tsum;
    #pragma unroll
    for (int d = 1; d < 64; d <<= 1) {
        int y = __shfl_up(x, d, 64);
        if (lane >= d) x += y;
    }
    if (lane == 63) wsum[wid] = x;
    __syncthreads();
    int woff = 0;
    for (int w = 0; w < wid; ++w) woff += wsum[w];
    int excl = base + woff + x - tsum;
    #pragma unroll
    for (int i = 0; i < 4; ++i) {
        int idx = idx0 + i;
        if (idx < N_NODES) { rp[idx] = excl; cnt[idx] = excl; }
        excl += v[i];
    }
}

// ---------------------------------------------------------------------------
// K4 (round-5 validated; gemm/scatter proportionally interleaved):
//   gemm blocks (1564): GEMM1 u16 = x16 @ M16t^T (128x128 tile)
//   scat blocks (1954): scatter edges -> payload {src, w} (CSR by tgt)
// A-tile direct-loaded (no LDS); B-tile staged + reused for C epilogue.
// ---------------------------------------------------------------------------
__global__ __launch_bounds__(256) void k4_gemmu_scatter_kernel(const __half* __restrict__ x16,
                                                               const __half* __restrict__ M16t,
                                                               __half* __restrict__ u16,
                                                               const int* __restrict__ ei,
                                                               const float* __restrict__ ew,
                                                               int* __restrict__ cnt,
                                                               int2* __restrict__ payload) {
    __shared__ __half Bm[128][136];   // 34,816 B; B-tile, then C staging
    const int tid = threadIdx.x;
    const int b = blockIdx.x;
    // proportional striping: exact NB_GEMM gemm slots, NB_SCAT scatter slots
    const int glo = (int)(((long long)b * NB_GEMM) / NB_K4);
    const int ghi = (int)(((long long)(b + 1) * NB_GEMM) / NB_K4);
    if (ghi == glo) {
        // ---- scatter (id = b - glo) ----
        int e = (b - glo) * 256 + tid;
        if (e < N_EDGES) {
            int s = ei[e], t = ei[N_EDGES + e];
            int pos = atomicAdd(&cnt[t], 1);
            payload[pos] = make_int2(s, __float_as_int(ew[e]));
        }
        return;
    }
    // ---- GEMM1 (id = glo) ----
    const int m0 = (glo % 391) * 128;
    const int colbase = (glo / 391) * 128;
    {
        const int r = tid >> 1, part = tid & 1;   // 64 halves = 8 uint4/thread
        const uint4* sb = (const uint4*)(M16t + (size_t)(colbase + r) * IN_CH + part * 64);
        uint4* db = (uint4*)&Bm[r][part * 64];
        #pragma unroll
        for (int q = 0; q < 8; ++q) db[q] = sb[q];
    }

    const int w = tid >> 6, lane = tid & 63;
    const int mrow = lane & 15, quad = lane >> 4;

    // A fragments: direct from x16 (each element consumed by exactly one lane)
    half8 a[2][4];
    #pragma unroll
    for (int mt = 0; mt < 2; ++mt) {
        int row = min(m0 + w * 32 + mt * 16 + mrow, N_NODES - 1); // pad rows read 49999; never stored
        const __half* ab = x16 + (size_t)row * IN_CH + quad * 8;
        #pragma unroll
        for (int ks = 0; ks < 4; ++ks) a[mt][ks] = *(const half8*)(ab + ks * 32);
    }
    __syncthreads();

    floatx4 acc[2][8];
    #pragma unroll
    for (int mt = 0; mt < 2; ++mt)
        #pragma unroll
        for (int nt = 0; nt < 8; ++nt)
            acc[mt][nt] = (floatx4){0.f, 0.f, 0.f, 0.f};

    #pragma unroll
    for (int nt = 0; nt < 8; ++nt) {
        #pragma unroll
        for (int ks = 0; ks < 4; ++ks) {
            half8 bfr = *(const half8*)&Bm[nt * 16 + mrow][ks * 32 + quad * 8];
            acc[0][nt] = __builtin_amdgcn_mfma_f32_16x16x32_f16(a[0][ks], bfr, acc[0][nt], 0, 0, 0);
            acc[1][nt] = __builtin_amdgcn_mfma_f32_16x16x32_f16(a[1][ks], bfr, acc[1][nt], 0, 0, 0);
        }
    }
    __syncthreads();   // all waves done reading Bm before overwrite
    #pragma unroll
    for (int mt = 0; mt < 2; ++mt)
        #pragma unroll
        for (int nt = 0; nt < 8; ++nt)
            #pragma unroll
            for (int r = 0; r < 4; ++r)
                Bm[w * 32 + mt * 16 + quad * 4 + r][nt * 16 + mrow] = __float2half(acc[mt][nt][r]);
    __syncthreads();
    {
        const int r = tid >> 1, part = tid & 1;
        if (m0 + r < N_NODES) {
            const uint4* s4 = (const uint4*)&Bm[r][part * 64];
            uint4* d4 = (uint4*)(u16 + (size_t)(m0 + r) * UDIM + colbase + part * 64);
            #pragma unroll
            for (int q = 0; q < 8; ++q) d4[q] = s4[q];
        }
    }
}

// ---------------------------------------------------------------------------
// Fused edge kernel v9: v8's async ring (validated) + p-GEMM epilogue.
// y is kept in LDS (never written to HBM: -51.2MB write, -51.2MB read), and
// each block contracts its own y tile against the L2-hot 64KB Zc16t:
//   p_h[node][64] = y_h[node][128] @ Zc_h[64][128]^T   (unnormalized)
// using the exact gemm_out fragment layout (wave w = head w, one 16-row
// m-tile, 4 n-tiles, 4 k-slices). finalize_kernel applies invs[h] + bias.
// LDS: ring 16KB + pbuf 3.5KB + y_lds 16.6KB = ~36.7KB -> 4 blocks/CU.
// ---------------------------------------------------------------------------
__global__ __launch_bounds__(256) void edge_fused_kernel(const __half* __restrict__ u16,
                                                         const __half* __restrict__ x16,
                                                         const int* __restrict__ rp,
                                                         const int* __restrict__ cnt,
                                                         const int2* __restrict__ payload,
                                                         const float* __restrict__ We,
                                                         const __half* __restrict__ Zc16t,
                                                         __half* __restrict__ p16,
                                                         double* __restrict__ S) {
    __shared__ __half xring[4][DEPTH][512];   // 16KB
    __shared__ __half y_lds[16][520];         // 16.6KB (stride 1040B: 2-way banks = free)
    __shared__ int2 pbuf[PCAP];               // 3.5KB
    __shared__ float sblk[4];
    const int tid = threadIdx.x;
    const int nodebase = blockIdx.x * 16;

    const int span0 = rp[nodebase];
    const int span1 = cnt[nodebase + 15];
    const int span  = span1 - span0;
    const int span_len = min(span, PCAP);
    for (int i = tid; i < span_len; i += 256) pbuf[i] = payload[span0 + i];
    if (tid < 4) sblk[tid] = 0.f;
    __syncthreads();

    const int w = tid >> 6, lane = tid & 63;
    const int g = lane >> 4;         // node-group within wave (0..3)
    const int l16 = lane & 15;
    const int h = l16 >> 2;          // head 0..3
    const int q = l16 & 3;           // channel quarter 0..3
    const int node = nodebase + (tid >> 4);
    const float wev = We[h];

    uint4 ur4[4];
    {
        const uint4* ub = (const uint4*)(u16 + (size_t)node * UDIM + h * 128 + q * 32);
        ur4[0] = ub[0]; ur4[1] = ub[1]; ur4[2] = ub[2]; ur4[3] = ub[3];
    }
    const half2_t* uh = (const half2_t*)ur4;    // 16 half2

    half2_t yacc[16];
    #pragma unroll
    for (int t = 0; t < 16; ++t) yacc[t] = (half2_t){(_Float16)0.f, (_Float16)0.f};

    float sacc = 0.f;
    const int start = rp[node];
    const int end = cnt[node];
    const int ng = end - start;

    if (span <= PCAP) {
        // ================= fast path: async ring =================
        int nmax = ng;
        nmax = max(nmax, __shfl_xor(nmax, 16, 64));
        nmax = max(nmax, __shfl_xor(nmax, 32, 64));
        if (nmax > 0) {
            // swizzled source chunk for this lane: chunk index = l16 ^ g (16B chunks)
            const int chunk_off = (l16 ^ g) * 8;   // in halves
            auto src_of = [&](int t) -> const __half* {
                int idx = min(start + t, end - 1);
                idx = max(idx, span0);             // ng==0 lanes clamp into valid span
                int s = pbuf[idx - span0].x;
                return x16 + (size_t)s * IN_CH + chunk_off;
            };
            #pragma unroll
            for (int s = 0; s < DEPTH; ++s)
                gll16(src_of(s), &xring[w][s][0]);

            for (int t = 0; t < nmax; ++t) {
                const int slot = t & (DEPTH - 1);
                asm volatile("s_waitcnt vmcnt(3)" ::: "memory");   // DEPTH-1
                __builtin_amdgcn_sched_barrier(0);
                // read this lane's 64B quarter (chunks q*4..q*4+3, de-swizzled)
                const uint4* rb = (const uint4*)&xring[w][slot][g * 128 + q * 32];
                uint4 xr0 = rb[0 ^ g];
                uint4 xr1 = rb[1 ^ g];
                uint4 xr2 = rb[2 ^ g];
                uint4 xr3 = rb[3 ^ g];
                asm volatile("s_waitcnt lgkmcnt(0)" ::: "memory"); // reads done before overwrite
                __builtin_amdgcn_sched_barrier(0);
                gll16(src_of(t + DEPTH), &xring[w][slot][0]);      // reissue (unconditional!)

                int2 pl;
                {
                    int idx = min(start + t, end - 1);
                    idx = max(idx, span0);
                    pl = pbuf[idx - span0];
                }
                uint4 xr[4] = {xr0, xr1, xr2, xr3};
                const half2_t* xh = (const half2_t*)xr;
                float d0 = 0.f, d1 = 0.f, d2 = 0.f, d3 = 0.f;
                #pragma unroll
                for (int tt = 0; tt < 4; ++tt) {
                    d0 = __builtin_amdgcn_fdot2(uh[tt],      xh[tt],      d0, false);
                    d1 = __builtin_amdgcn_fdot2(uh[tt + 4],  xh[tt + 4],  d1, false);
                    d2 = __builtin_amdgcn_fdot2(uh[tt + 8],  xh[tt + 8],  d2, false);
                    d3 = __builtin_amdgcn_fdot2(uh[tt + 12], xh[tt + 12], d3, false);
                }
                float dot = (d0 + d1) + (d2 + d3);
                dot += dpp_xor1(dot);
                dot += dpp_xor2(dot);            // sum over the 4 q-lanes (one aligned quad)
                float l = dot * 0.125f + __int_as_float(pl.y) * wev;
                l = fmaxf(l, 0.2f * l);          // leaky_relu(0.2)
                float p = __expf(l);
                if (t < ng) {
                    if (q == 0) sacc += p;
                    half2_t p2 = (half2_t){(_Float16)p, (_Float16)p};
                    #pragma unroll
                    for (int tt = 0; tt < 16; ++tt)
                        yacc[tt] = p2 * xh[tt] + yacc[tt];   // v_pk_fma_f16
                }
            }
        }
    } else {
        // ================= slow path (span > PCAP, ~never) =================
        auto getpl = [&](int e) -> int2 {
            int idx = e - span0;
            return (idx < PCAP) ? pbuf[idx] : payload[e];
        };
        int2 pl = make_int2(0, 0);
        uint4 xr[4];
        if (start < end) {
            pl = getpl(start);
            const uint4* xb = (const uint4*)(x16 + (size_t)pl.x * IN_CH + q * 32);
            xr[0] = xb[0]; xr[1] = xb[1]; xr[2] = xb[2]; xr[3] = xb[3];
        }
        for (int e = start; e < end; ++e) {
            int2 pln = pl;
            uint4 xrn[4] = {xr[0], xr[1], xr[2], xr[3]};
            if (e + 1 < end) {
                pln = getpl(e + 1);
                const uint4* xb = (const uint4*)(x16 + (size_t)pln.x * IN_CH + q * 32);
                xrn[0] = xb[0]; xrn[1] = xb[1]; xrn[2] = xb[2]; xrn[3] = xb[3];
            }
            const half2_t* xh = (const half2_t*)xr;
            float dot = 0.f;
            #pragma unroll
            for (int t = 0; t < 16; ++t)
                dot = __builtin_amdgcn_fdot2(uh[t], xh[t], dot, false);
            dot += __shfl_xor(dot, 1, 16);
            dot += __shfl_xor(dot, 2, 16);
            float l = dot * 0.125f + __int_as_float(pl.y) * wev;
            l = fmaxf(l, 0.2f * l);
            float p = __expf(l);
            if (q == 0) sacc += p;
            half2_t p2 = (half2_t){(_Float16)p, (_Float16)p};
            #pragma unroll
            for (int t = 0; t < 16; ++t)
                yacc[t] = p2 * xh[t] + yacc[t];
            pl = pln;
            xr[0] = xrn[0]; xr[1] = xrn[1]; xr[2] = xrn[2]; xr[3] = xrn[3];
        }
    }
    // ---- y -> LDS (replaces the HBM y16 store) ----
    {
        uint4* yo = (uint4*)&y_lds[tid >> 4][h * 128 + q * 32];
        const uint4* ys = (const uint4*)yacc;
        yo[0] = ys[0]; yo[1] = ys[1]; yo[2] = ys[2]; yo[3] = ys[3];
    }
    if (q == 0) atomicAdd(&sblk[h], sacc);
    __syncthreads();   // y_lds visible + sblk complete
    if (tid < 4) atomicAdd(&S[tid], (double)sblk[tid]);

    // ---- p-GEMM epilogue: wave w computes head w (validated fragment layout)
    {
        const int hh = w;
        const int mrow = lane & 15, quad = lane >> 4;
        half8 a2[4];
        #pragma unroll
        for (int ks = 0; ks < 4; ++ks)
            a2[ks] = *(const half8*)&y_lds[mrow][hh * 128 + ks * 32 + quad * 8];
        #pragma unroll
        for (int nt = 0; nt < 4; ++nt) {
            floatx4 acc = (floatx4){0.f, 0.f, 0.f, 0.f};
            const __half* bb = Zc16t + (size_t)(nt * 16 + mrow) * UDIM + hh * 128 + quad * 8;
            #pragma unroll
            for (int ks = 0; ks < 4; ++ks) {
                half8 bfr = *(const half8*)(bb + ks * 32);
                acc = __builtin_amdgcn_mfma_f32_16x16x32_f16(a2[ks], bfr, acc, 0, 0, 0);
            }
            // C[arow=quad*4+r][bcol=nt*16+mrow] -> p16[node][hh*64 + c]
            #pragma unroll
            for (int r = 0; r < 4; ++r)
                p16[(size_t)(nodebase + quad * 4 + r) * D + hh * 64 + nt * 16 + mrow] =
                    __float2half(acc[r]);
        }
    }
}

// ---------------------------------------------------------------------------
// Finalize: out[n][c] = sum_h (1/S[h]) * p_h[n][c] + b_out[c].  Elementwise,
// 12500 blocks, fully coalesced (replaces the 23-27us gemm_out).
// ---------------------------------------------------------------------------
__global__ __launch_bounds__(256) void finalize_kernel(const __half* __restrict__ p16,
                                                       const double* __restrict__ S,
                                                       const float* __restrict__ b_out,
                                                       float* __restrict__ out) {
    const int idx = blockIdx.x * 256 + threadIdx.x;   // 50000*64 exact
    const int n = idx >> 6, c = idx & 63;
    const float i0 = (float)(1.0 / S[0]);
    const float i1 = (float)(1.0 / S[1]);
    const float i2 = (float)(1.0 / S[2]);
    const float i3 = (float)(1.0 / S[3]);
    const __half* pr = p16 + (size_t)n * D + c;
    float v = __half2float(pr[0])   * i0
            + __half2float(pr[64])  * i1
            + __half2float(pr[128]) * i2
            + __half2float(pr[192]) * i3;
    out[(size_t)n * OUT_CH + c] = v + b_out[c];
}

// ---------------------------------------------------------------------------
// Launch
// ---------------------------------------------------------------------------
extern "C" void kernel_launch(void* const* d_in, const int* in_sizes, int n_in,
                              void* d_out, int out_size, void* d_ws, size_t ws_size,
                              hipStream_t stream) {
    const float* x     = (const float*)d_in[0];
    const int*   ei    = (const int*)d_in[1];   // [2, E] int32
    const float* ew    = (const float*)d_in[2];
    const float* Wq    = (const float*)d_in[3];
    const float* Wk    = (const float*)d_in[4];
    const float* Wv    = (const float*)d_in[5];
    const float* We    = (const float*)d_in[6];
    const float* Wout  = (const float*)d_in[7];
    const float* b_out = (const float*)d_in[8];
    float* out = (float*)d_out;

    // workspace layout (p16 reuses the old y16 slot; layout otherwise unchanged)
    __half* u16   = (__half*)d_ws;                          // 50000*512*2 = 51.2 MB
    __half* p16   = u16 + (size_t)N_NODES * UDIM;           // 50000*256*2 = 25.6 MB
    __half* x16   = p16 + (size_t)N_NODES * UDIM;           // 12.8 MB (offset kept)
    double* S     = (double*)(x16 + (size_t)N_NODES * IN_CH);  // 4 doubles
    __half* M16t  = (__half*)(S + HEADS);                   // 512*128*2 = 128 KB
    __half* Zc16t = M16t + UDIM * IN_CH;                    // 64*512*2 = 64 KB
    int*    rp    = (int*)(Zc16t + OUT_CH * UDIM);          // 50000
    int*    cnt   = rp + N_NODES;                           // 50000
    int*    csum  = cnt + N_NODES;                          // 64
    int2*   payload = (int2*)(csum + 64);                   // 500000*8 = 4 MB

    hipMemsetAsync(cnt, 0, N_NODES * sizeof(int), stream);
    k1_prep_kernel<<<NB_X16 + NB_HIST + NB_MB + NB_ZB, 256, 0, stream>>>(
        x, x16, ei, cnt, S, Wq, Wk, Wv, Wout, M16t, Zc16t);
    k2_scan_reduce_kernel<<<NC, 256, 0, stream>>>(cnt, csum);
    k3_scan_chunks_kernel<<<NC, 256, 0, stream>>>(cnt, csum, rp);
    k4_gemmu_scatter_kernel<<<NB_K4, 256, 0, stream>>>(
        x16, M16t, u16, ei, ew, cnt, payload);
    edge_fused_kernel<<<N_NODES / 16, 256, 0, stream>>>(
        u16, x16, rp, cnt, payload, We, Zc16t, p16, S);
    finalize_kernel<<<(N_NODES * OUT_CH) / 256, 256, 0, stream>>>(p16, S, b_out, out);
}

// Round 10
// 235.535 us; speedup vs baseline: 1.1293x; 1.0096x over previous
//
#include <hip/hip_runtime.h>
#include <hip/hip_bf16.h>
#include <hip/hip_fp16.h>

// Problem constants
#define N_NODES 50000
#define N_EDGES 500000
#define IN_CH   128
#define D       256   // HEADS * OUT_CH
#define UDIM    512   // HEADS * 128 (u and y width)
#define OUT_CH  64
#define HEADS   4
#define NC      49    // scan chunks of 1024: ceil(50000/1024)
#define PCAP    448   // LDS payload staging capacity per block (span ~ Poisson(160))
#define DEPTH   4     // async x-gather ring depth (per wave)

// K1 grid sections
#define NB_X16  6250  // 50000*128/4/256
#define NB_HIST 1954  // ceil(500000/256)
#define NB_MB   256   // 512 M-rows, 2 per block
#define NB_ZB   128   // 512 Zc-rows, 4 per block
// K4 grid sections (gemm_u || scatter, proportionally interleaved) — round-5 validated
#define NB_GEMM 1564  // 391 * 4
#define NB_SCAT 1954  // ceil(500000/256)
#define NB_K4   (NB_GEMM + NB_SCAT)

typedef _Float16 half8 __attribute__((ext_vector_type(8)));   // 4 VGPRs (MFMA A/B)
typedef _Float16 half2_t __attribute__((ext_vector_type(2))); // 1 VGPR packed
typedef float   floatx4 __attribute__((ext_vector_type(4)));  // 4 VGPRs (MFMA C/D)

typedef __attribute__((address_space(1))) const void as1_void;
typedef __attribute__((address_space(3))) void as3_void;

__device__ __forceinline__ void gll16(const void* g, void* l) {
    __builtin_amdgcn_global_load_lds((as1_void*)g, (as3_void*)l, 16, 0, 0);
}

// DPP quad-perm butterfly adds (4 q-lanes of one head form one aligned quad)
__device__ __forceinline__ float dpp_xor1(float x) {
    return __int_as_float(__builtin_amdgcn_mov_dpp(__float_as_int(x), 0xB1, 0xf, 0xf, true));
}
__device__ __forceinline__ float dpp_xor2(float x) {
    return __int_as_float(__builtin_amdgcn_mov_dpp(__float_as_int(x), 0x4E, 0xf, 0xf, true));
}

// ---------------------------------------------------------------------------
// K1 (fused): x16 convert | tgt histogram | M16t build | Zc16t build
// ---------------------------------------------------------------------------
__global__ __launch_bounds__(256) void k1_prep_kernel(const float* __restrict__ x,
                                                      __half* __restrict__ x16,
                                                      const int* __restrict__ ei,
                                                      int* __restrict__ cnt,
                                                      double* __restrict__ S,
                                                      const float* __restrict__ Wq,
                                                      const float* __restrict__ Wk,
                                                      const float* __restrict__ Wv,
                                                      const float* __restrict__ Wout,
                                                      __half* __restrict__ M16t,
                                                      __half* __restrict__ Zc16t) {
    __shared__ float sbuf[4][64];
    const int b = blockIdx.x, tid = threadIdx.x;
    if (b < NB_X16) {
        int i = b * 256 + tid;
        if (i < HEADS) S[i] = 0.0;
        int k = i * 4;
        if (k < N_NODES * IN_CH) {
            float4 v = *(const float4*)(x + k);
            union { __half2 h[2]; uint2 u; } pk;
            pk.h[0] = __floats2half2_rn(v.x, v.y);
            pk.h[1] = __floats2half2_rn(v.z, v.w);
            *(uint2*)(x16 + k) = pk.u;
        }
    } else if (b < NB_X16 + NB_HIST) {
        int e = (b - NB_X16) * 256 + tid;
        if (e < N_EDGES) atomicAdd(&cnt[ei[N_EDGES + e]], 1);
    } else if (b < NB_X16 + NB_HIST + NB_MB) {
        const int r = (b - NB_X16 - NB_HIST) * 2 + (tid >> 7);  // M-row 0..511
        const int i = tid & 127;
        const int h = r >> 7, j = r & 127;
        float* buf = sbuf[tid >> 7];
        if (i < 64) buf[i] = Wk[(size_t)j * D + h * 64 + i];
        __syncthreads();
        const float4* qr = (const float4*)(Wq + (size_t)i * D + h * 64);
        float s = 0.f;
        #pragma unroll
        for (int c4 = 0; c4 < 16; ++c4) {
            float4 q = qr[c4];
            s += q.x * buf[c4 * 4] + q.y * buf[c4 * 4 + 1]
               + q.z * buf[c4 * 4 + 2] + q.w * buf[c4 * 4 + 3];
        }
        M16t[(size_t)r * IN_CH + i] = __float2half(s);
    } else {
        const int r = (b - NB_X16 - NB_HIST - NB_MB) * 4 + (tid >> 6); // Zc-row
        const int c = tid & 63;
        const int h = r >> 7, i = r & 127;
        float* buf = sbuf[tid >> 6];
        buf[c] = Wv[(size_t)i * D + h * 64 + c];
        __syncthreads();
        float s = 0.f;
        #pragma unroll 8
        for (int j = 0; j < 64; ++j)
            s += buf[j] * Wout[(size_t)(h * 64 + j) * OUT_CH + c];
        Zc16t[(size_t)c * UDIM + r] = __float2half(s);
    }
}

// ---------------------------------------------------------------------------
// K2: scan_reduce — per-1024-chunk sums of cnt into csum (49 blocks)
// ---------------------------------------------------------------------------
__global__ __launch_bounds__(256) void k2_scan_reduce_kernel(const int* __restrict__ cnt,
                                                             int* __restrict__ csum) {
    const int b = blockIdx.x, tid = threadIdx.x;
    const int lane = tid & 63, wid = tid >> 6;
    int s = 0;
    int idx0 = b * 1024 + tid * 4;
    #pragma unroll
    for (int i = 0; i < 4; ++i) {
        int idx = idx0 + i;
        if (idx < N_NODES) s += cnt[idx];
    }
    #pragma unroll
    for (int m = 1; m < 64; m <<= 1) s += __shfl_xor(s, m, 64);
    __shared__ int w4[4];
    if (lane == 0) w4[wid] = s;
    __syncthreads();
    if (tid == 0) csum[b] = w4[0] + w4[1] + w4[2] + w4[3];
}

// ---------------------------------------------------------------------------
// K3: scan_chunks with inlined 49-element top-scan
// ---------------------------------------------------------------------------
__global__ __launch_bounds__(256) void k3_scan_chunks_kernel(int* __restrict__ cnt,
                                                             const int* __restrict__ csum,
                                                             int* __restrict__ rp) {
    __shared__ int stop[64];
    __shared__ int wsum[4];
    const int b = blockIdx.x, tid = threadIdx.x;
    const int lane = tid & 63, wid = tid >> 6;
    if (tid < 64) stop[tid] = (tid < NC) ? csum[tid] : 0;
    __syncthreads();
    int base = 0;
    for (int w = 0; w < b; ++w) base += stop[w];
    int v[4];
    const int idx0 = b * 1024 + tid * 4;
    #pragma unroll
    for (int i = 0; i < 4; ++i) {
        int idx = idx0 + i;
        v[i] = (idx < N_NODES) ? cnt[idx] : 0;
    }
    int tsum = v[0] + v[1] + v[2] + v[3];
    int x = tsum;
    #pragma unroll
    for (int d = 1; d < 64; d <<= 1) {
        int y = __shfl_up(x, d, 64);
        if (lane >= d) x += y;
    }
    if (lane == 63) wsum[wid] = x;
    __syncthreads();
    int woff = 0;
    for (int w = 0; w < wid; ++w) woff += wsum[w];
    int excl = base + woff + x - tsum;
    #pragma unroll
    for (int i = 0; i < 4; ++i) {
        int idx = idx0 + i;
        if (idx < N_NODES) { rp[idx] = excl; cnt[idx] = excl; }
        excl += v[i];
    }
}

// ---------------------------------------------------------------------------
// K4 (round-5 validated; gemm/scatter proportionally interleaved):
//   gemm blocks (1564): GEMM1 u16 = x16 @ M16t^T (128x128 tile)
//   scat blocks (1954): scatter edges -> payload {src, w} (CSR by tgt)
// A-tile direct-loaded (no LDS); B-tile staged + reused for C epilogue.
// ---------------------------------------------------------------------------
__global__ __launch_bounds__(256) void k4_gemmu_scatter_kernel(const __half* __restrict__ x16,
                                                               const __half* __restrict__ M16t,
                                                               __half* __restrict__ u16,
                                                               const int* __restrict__ ei,
                                                               const float* __restrict__ ew,
                                                               int* __restrict__ cnt,
                                                               int2* __restrict__ payload) {
    __shared__ __half Bm[128][136];   // 34,816 B; B-tile, then C staging
    const int tid = threadIdx.x;
    const int b = blockIdx.x;
    // proportional striping: exact NB_GEMM gemm slots, NB_SCAT scatter slots
    const int glo = (int)(((long long)b * NB_GEMM) / NB_K4);
    const int ghi = (int)(((long long)(b + 1) * NB_GEMM) / NB_K4);
    if (ghi == glo) {
        // ---- scatter (id = b - glo) ----
        int e = (b - glo) * 256 + tid;
        if (e < N_EDGES) {
            int s = ei[e], t = ei[N_EDGES + e];
            int pos = atomicAdd(&cnt[t], 1);
            payload[pos] = make_int2(s, __float_as_int(ew[e]));
        }
        return;
    }
    // ---- GEMM1 (id = glo) ----
    const int m0 = (glo % 391) * 128;
    const int colbase = (glo / 391) * 128;
    {
        const int r = tid >> 1, part = tid & 1;   // 64 halves = 8 uint4/thread
        const uint4* sb = (const uint4*)(M16t + (size_t)(colbase + r) * IN_CH + part * 64);
        uint4* db = (uint4*)&Bm[r][part * 64];
        #pragma unroll
        for (int q = 0; q < 8; ++q) db[q] = sb[q];
    }

    const int w = tid >> 6, lane = tid & 63;
    const int mrow = lane & 15, quad = lane >> 4;

    // A fragments: direct from x16 (each element consumed by exactly one lane)
    half8 a[2][4];
    #pragma unroll
    for (int mt = 0; mt < 2; ++mt) {
        int row = min(m0 + w * 32 + mt * 16 + mrow, N_NODES - 1); // pad rows read 49999; never stored
        const __half* ab = x16 + (size_t)row * IN_CH + quad * 8;
        #pragma unroll
        for (int ks = 0; ks < 4; ++ks) a[mt][ks] = *(const half8*)(ab + ks * 32);
    }
    __syncthreads();

    floatx4 acc[2][8];
    #pragma unroll
    for (int mt = 0; mt < 2; ++mt)
        #pragma unroll
        for (int nt = 0; nt < 8; ++nt)
            acc[mt][nt] = (floatx4){0.f, 0.f, 0.f, 0.f};

    #pragma unroll
    for (int nt = 0; nt < 8; ++nt) {
        #pragma unroll
        for (int ks = 0; ks < 4; ++ks) {
            half8 bfr = *(const half8*)&Bm[nt * 16 + mrow][ks * 32 + quad * 8];
            acc[0][nt] = __builtin_amdgcn_mfma_f32_16x16x32_f16(a[0][ks], bfr, acc[0][nt], 0, 0, 0);
            acc[1][nt] = __builtin_amdgcn_mfma_f32_16x16x32_f16(a[1][ks], bfr, acc[1][nt], 0, 0, 0);
        }
    }
    __syncthreads();   // all waves done reading Bm before overwrite
    #pragma unroll
    for (int mt = 0; mt < 2; ++mt)
        #pragma unroll
        for (int nt = 0; nt < 8; ++nt)
            #pragma unroll
            for (int r = 0; r < 4; ++r)
                Bm[w * 32 + mt * 16 + quad * 4 + r][nt * 16 + mrow] = __float2half(acc[mt][nt][r]);
    __syncthreads();
    {
        const int r = tid >> 1, part = tid & 1;
        if (m0 + r < N_NODES) {
            const uint4* s4 = (const uint4*)&Bm[r][part * 64];
            uint4* d4 = (uint4*)(u16 + (size_t)(m0 + r) * UDIM + colbase + part * 64);
            #pragma unroll
            for (int q = 0; q < 8; ++q) d4[q] = s4[q];
        }
    }
}

// ---------------------------------------------------------------------------
// Fused edge kernel v10: v9's ring + p-GEMM epilogue, with the p16 store
// COALESCED: C fragments are staged in LDS (reusing the dead ring buffer —
// all in-flight global_load_lds drain at the barrier) and written out as
// 16B uint4 stores (512B/row) instead of 4096 scattered 2B stores/block.
// ---------------------------------------------------------------------------
__global__ __launch_bounds__(256) void edge_fused_kernel(const __half* __restrict__ u16,
                                                         const __half* __restrict__ x16,
                                                         const int* __restrict__ rp,
                                                         const int* __restrict__ cnt,
                                                         const int2* __restrict__ payload,
                                                         const float* __restrict__ We,
                                                         const __half* __restrict__ Zc16t,
                                                         __half* __restrict__ p16,
                                                         double* __restrict__ S) {
    __shared__ __half xring[4][DEPTH][512];   // 16KB; reused as p_lds[16][264] in epilogue
    __shared__ __half y_lds[16][520];         // 16.6KB
    __shared__ int2 pbuf[PCAP];               // 3.5KB
    __shared__ float sblk[4];
    const int tid = threadIdx.x;
    const int nodebase = blockIdx.x * 16;

    const int span0 = rp[nodebase];
    const int span1 = cnt[nodebase + 15];
    const int span  = span1 - span0;
    const int span_len = min(span, PCAP);
    for (int i = tid; i < span_len; i += 256) pbuf[i] = payload[span0 + i];
    if (tid < 4) sblk[tid] = 0.f;
    __syncthreads();

    const int w = tid >> 6, lane = tid & 63;
    const int g = lane >> 4;         // node-group within wave (0..3)
    const int l16 = lane & 15;
    const int h = l16 >> 2;          // head 0..3
    const int q = l16 & 3;           // channel quarter 0..3
    const int node = nodebase + (tid >> 4);
    const float wev = We[h];

    uint4 ur4[4];
    {
        const uint4* ub = (const uint4*)(u16 + (size_t)node * UDIM + h * 128 + q * 32);
        ur4[0] = ub[0]; ur4[1] = ub[1]; ur4[2] = ub[2]; ur4[3] = ub[3];
    }
    const half2_t* uh = (const half2_t*)ur4;    // 16 half2

    half2_t yacc[16];
    #pragma unroll
    for (int t = 0; t < 16; ++t) yacc[t] = (half2_t){(_Float16)0.f, (_Float16)0.f};

    float sacc = 0.f;
    const int start = rp[node];
    const int end = cnt[node];
    const int ng = end - start;

    if (span <= PCAP) {
        // ================= fast path: async ring =================
        int nmax = ng;
        nmax = max(nmax, __shfl_xor(nmax, 16, 64));
        nmax = max(nmax, __shfl_xor(nmax, 32, 64));
        if (nmax > 0) {
            // swizzled source chunk for this lane: chunk index = l16 ^ g (16B chunks)
            const int chunk_off = (l16 ^ g) * 8;   // in halves
            auto src_of = [&](int t) -> const __half* {
                int idx = min(start + t, end - 1);
                idx = max(idx, span0);             // ng==0 lanes clamp into valid span
                int s = pbuf[idx - span0].x;
                return x16 + (size_t)s * IN_CH + chunk_off;
            };
            #pragma unroll
            for (int s = 0; s < DEPTH; ++s)
                gll16(src_of(s), &xring[w][s][0]);

            for (int t = 0; t < nmax; ++t) {
                const int slot = t & (DEPTH - 1);
                asm volatile("s_waitcnt vmcnt(3)" ::: "memory");   // DEPTH-1
                __builtin_amdgcn_sched_barrier(0);
                // read this lane's 64B quarter (chunks q*4..q*4+3, de-swizzled)
                const uint4* rb = (const uint4*)&xring[w][slot][g * 128 + q * 32];
                uint4 xr0 = rb[0 ^ g];
                uint4 xr1 = rb[1 ^ g];
                uint4 xr2 = rb[2 ^ g];
                uint4 xr3 = rb[3 ^ g];
                asm volatile("s_waitcnt lgkmcnt(0)" ::: "memory"); // reads done before overwrite
                __builtin_amdgcn_sched_barrier(0);
                gll16(src_of(t + DEPTH), &xring[w][slot][0]);      // reissue (unconditional!)

                int2 pl;
                {
                    int idx = min(start + t, end - 1);
                    idx = max(idx, span0);
                    pl = pbuf[idx - span0];
                }
                uint4 xr[4] = {xr0, xr1, xr2, xr3};
                const half2_t* xh = (const half2_t*)xr;
                float d0 = 0.f, d1 = 0.f, d2 = 0.f, d3 = 0.f;
                #pragma unroll
                for (int tt = 0; tt < 4; ++tt) {
                    d0 = __builtin_amdgcn_fdot2(uh[tt],      xh[tt],      d0, false);
                    d1 = __builtin_amdgcn_fdot2(uh[tt + 4],  xh[tt + 4],  d1, false);
                    d2 = __builtin_amdgcn_fdot2(uh[tt + 8],  xh[tt + 8],  d2, false);
                    d3 = __builtin_amdgcn_fdot2(uh[tt + 12], xh[tt + 12], d3, false);
                }
                float dot = (d0 + d1) + (d2 + d3);
                dot += dpp_xor1(dot);
                dot += dpp_xor2(dot);            // sum over the 4 q-lanes (one aligned quad)
                float l = dot * 0.125f + __int_as_float(pl.y) * wev;
                l = fmaxf(l, 0.2f * l);          // leaky_relu(0.2)
                float p = __expf(l);
                if (t < ng) {
                    if (q == 0) sacc += p;
                    half2_t p2 = (half2_t){(_Float16)p, (_Float16)p};
                    #pragma unroll
                    for (int tt = 0; tt < 16; ++tt)
                        yacc[tt] = p2 * xh[tt] + yacc[tt];   // v_pk_fma_f16
                }
            }
        }
    } else {
        // ================= slow path (span > PCAP, ~never) =================
        auto getpl = [&](int e) -> int2 {
            int idx = e - span0;
            return (idx < PCAP) ? pbuf[idx] : payload[e];
        };
        int2 pl = make_int2(0, 0);
        uint4 xr[4];
        if (start < end) {
            pl = getpl(start);
            const uint4* xb = (const uint4*)(x16 + (size_t)pl.x * IN_CH + q * 32);
            xr[0] = xb[0]; xr[1] = xb[1]; xr[2] = xb[2]; xr[3] = xb[3];
        }
        for (int e = start; e < end; ++e) {
            int2 pln = pl;
            uint4 xrn[4] = {xr[0], xr[1], xr[2], xr[3]};
            if (e + 1 < end) {
                pln = getpl(e + 1);
                const uint4* xb = (const uint4*)(x16 + (size_t)pln.x * IN_CH + q * 32);
                xrn[0] = xb[0]; xrn[1] = xb[1]; xrn[2] = xb[2]; xrn[3] = xb[3];
            }
            const half2_t* xh = (const half2_t*)xr;
            float dot = 0.f;
            #pragma unroll
            for (int t = 0; t < 16; ++t)
                dot = __builtin_amdgcn_fdot2(uh[t], xh[t], dot, false);
            dot += __shfl_xor(dot, 1, 16);
            dot += __shfl_xor(dot, 2, 16);
            float l = dot * 0.125f + __int_as_float(pl.y) * wev;
            l = fmaxf(l, 0.2f * l);
            float p = __expf(l);
            if (q == 0) sacc += p;
            half2_t p2 = (half2_t){(_Float16)p, (_Float16)p};
            #pragma unroll
            for (int t = 0; t < 16; ++t)
                yacc[t] = p2 * xh[t] + yacc[t];
            pl = pln;
            xr[0] = xrn[0]; xr[1] = xrn[1]; xr[2] = xrn[2]; xr[3] = xrn[3];
        }
    }
    // ---- y -> LDS (replaces the HBM y16 store) ----
    {
        uint4* yo = (uint4*)&y_lds[tid >> 4][h * 128 + q * 32];
        const uint4* ys = (const uint4*)yacc;
        yo[0] = ys[0]; yo[1] = ys[1]; yo[2] = ys[2]; yo[3] = ys[3];
    }
    if (q == 0) atomicAdd(&sblk[h], sacc);
    __syncthreads();   // y_lds visible + sblk complete + ALL ring loads drained
    if (tid < 4) atomicAdd(&S[tid], (double)sblk[tid]);

    // ---- p-GEMM epilogue: wave w computes head w; fragments staged to LDS
    //      (overlaying the dead ring buffer), then stored coalesced.
    {
        const int hh = w;
        const int mrow = lane & 15, quad = lane >> 4;
        __half* p_lds = &xring[0][0][0];   // [16][264] tile, stride 528B
        half8 a2[4];
        #pragma unroll
        for (int ks = 0; ks < 4; ++ks)
            a2[ks] = *(const half8*)&y_lds[mrow][hh * 128 + ks * 32 + quad * 8];
        #pragma unroll
        for (int nt = 0; nt < 4; ++nt) {
            floatx4 acc = (floatx4){0.f, 0.f, 0.f, 0.f};
            const __half* bb = Zc16t + (size_t)(nt * 16 + mrow) * UDIM + hh * 128 + quad * 8;
            #pragma unroll
            for (int ks = 0; ks < 4; ++ks) {
                half8 bfr = *(const half8*)(bb + ks * 32);
                acc = __builtin_amdgcn_mfma_f32_16x16x32_f16(a2[ks], bfr, acc, 0, 0, 0);
            }
            // C[arow=quad*4+r][bcol=nt*16+mrow] -> p_lds[row][hh*64 + col]
            #pragma unroll
            for (int r = 0; r < 4; ++r)
                p_lds[(quad * 4 + r) * 264 + hh * 64 + nt * 16 + mrow] = __float2half(acc[r]);
        }
    }
    __syncthreads();   // p_lds tile complete
    {
        const __half* p_lds = &xring[0][0][0];
        const int row = tid >> 4, part = tid & 15;   // 16 threads/row x 32B = 512B
        uint4 v0 = *(const uint4*)&p_lds[row * 264 + part * 16];
        uint4 v1 = *(const uint4*)&p_lds[row * 264 + part * 16 + 8];
        uint4* dst = (uint4*)(p16 + (size_t)(nodebase + row) * D + part * 16);
        dst[0] = v0;
        dst[1] = v1;
    }
}

// ---------------------------------------------------------------------------
// Finalize: out[n][c] = sum_h (1/S[h]) * p_h[n][c] + b_out[c].  Elementwise,
// fully coalesced.
// ---------------------------------------------------------------------------
__global__ __launch_bounds__(256) void finalize_kernel(const __half* __restrict__ p16,
                                                       const double* __restrict__ S,
                                                       const float* __restrict__ b_out,
                                                       float* __restrict__ out) {
    const int idx = blockIdx.x * 256 + threadIdx.x;   // 50000*64 exact
    const int n = idx >> 6, c = idx & 63;
    const float i0 = (float)(1.0 / S[0]);
    const float i1 = (float)(1.0 / S[1]);
    const float i2 = (float)(1.0 / S[2]);
    const float i3 = (float)(1.0 / S[3]);
    const __half* pr = p16 + (size_t)n * D + c;
    float v = __half2float(pr[0])   * i0
            + __half2float(pr[64])  * i1
            + __half2float(pr[128]) * i2
            + __half2float(pr[192]) * i3;
    out[(size_t)n * OUT_CH + c] = v + b_out[c];
}

// ---------------------------------------------------------------------------
// Launch
// ---------------------------------------------------------------------------
extern "C" void kernel_launch(void* const* d_in, const int* in_sizes, int n_in,
                              void* d_out, int out_size, void* d_ws, size_t ws_size,
                              hipStream_t stream) {
    const float* x     = (const float*)d_in[0];
    const int*   ei    = (const int*)d_in[1];   // [2, E] int32
    const float* ew    = (const float*)d_in[2];
    const float* Wq    = (const float*)d_in[3];
    const float* Wk    = (const float*)d_in[4];
    const float* Wv    = (const float*)d_in[5];
    const float* We    = (const float*)d_in[6];
    const float* Wout  = (const float*)d_in[7];
    const float* b_out = (const float*)d_in[8];
    float* out = (float*)d_out;

    // workspace layout (p16 reuses the old y16 slot; layout otherwise unchanged)
    __half* u16   = (__half*)d_ws;                          // 50000*512*2 = 51.2 MB
    __half* p16   = u16 + (size_t)N_NODES * UDIM;           // 50000*256*2 = 25.6 MB
    __half* x16   = p16 + (size_t)N_NODES * UDIM;           // 12.8 MB (offset kept)
    double* S     = (double*)(x16 + (size_t)N_NODES * IN_CH);  // 4 doubles
    __half* M16t  = (__half*)(S + HEADS);                   // 512*128*2 = 128 KB
    __half* Zc16t = M16t + UDIM * IN_CH;                    // 64*512*2 = 64 KB
    int*    rp    = (int*)(Zc16t + OUT_CH * UDIM);          // 50000
    int*    cnt   = rp + N_NODES;                           // 50000
    int*    csum  = cnt + N_NODES;                          // 64
    int2*   payload = (int2*)(csum + 64);                   // 500000*8 = 4 MB

    hipMemsetAsync(cnt, 0, N_NODES * sizeof(int), stream);
    k1_prep_kernel<<<NB_X16 + NB_HIST + NB_MB + NB_ZB, 256, 0, stream>>>(
        x, x16, ei, cnt, S, Wq, Wk, Wv, Wout, M16t, Zc16t);
    k2_scan_reduce_kernel<<<NC, 256, 0, stream>>>(cnt, csum);
    k3_scan_chunks_kernel<<<NC, 256, 0, stream>>>(cnt, csum, rp);
    k4_gemmu_scatter_kernel<<<NB_K4, 256, 0, stream>>>(
        x16, M16t, u16, ei, ew, cnt, payload);
    edge_fused_kernel<<<N_NODES / 16, 256, 0, stream>>>(
        u16, x16, rp, cnt, payload, We, Zc16t, p16, S);
    finalize_kernel<<<(N_NODES * OUT_CH) / 256, 256, 0, stream>>>(p16, S, b_out, out);
}

// Round 11
// 234.636 us; speedup vs baseline: 1.1337x; 1.0038x over previous
//
#include <hip/hip_runtime.h>
#include <hip/hip_bf16.h>
#include <hip/hip_fp16.h>

// Problem constants
#define N_NODES 50000
#define N_EDGES 500000
#define IN_CH   128
#define D       256   // HEADS * OUT_CH
#define UDIM    512   // HEADS * 128 (u and y width)
#define OUT_CH  64
#define HEADS   4
#define NC      49    // scan chunks of 1024: ceil(50000/1024)
#define PCAP    448   // LDS payload staging capacity per block (span ~ Poisson(160))
#define DEPTH   4     // async x-gather ring depth (per wave)

// K1 grid sections
#define NB_X16  6250  // 50000*128/4/256
#define NB_HIST 1954  // ceil(500000/256)
#define NB_MB   256   // 512 M-rows, 2 per block
#define NB_ZB   128   // 512 Zc-rows, 4 per block
// K4 grid sections (gemm_u || scatter, proportionally interleaved) — round-5 validated
#define NB_GEMM 1564  // 391 * 4
#define NB_SCAT 1954  // ceil(500000/256)
#define NB_K4   (NB_GEMM + NB_SCAT)

typedef _Float16 half8 __attribute__((ext_vector_type(8)));   // 4 VGPRs (MFMA A/B)
typedef _Float16 half2_t __attribute__((ext_vector_type(2))); // 1 VGPR packed
typedef float   floatx4 __attribute__((ext_vector_type(4)));  // 4 VGPRs (MFMA C/D)

typedef __attribute__((address_space(1))) const void as1_void;
typedef __attribute__((address_space(3))) void as3_void;

__device__ __forceinline__ void gll16(const void* g, void* l) {
    __builtin_amdgcn_global_load_lds((as1_void*)g, (as3_void*)l, 16, 0, 0);
}

// DPP quad-perm butterfly adds (4 q-lanes of one head form one aligned quad)
__device__ __forceinline__ float dpp_xor1(float x) {
    return __int_as_float(__builtin_amdgcn_mov_dpp(__float_as_int(x), 0xB1, 0xf, 0xf, true));
}
__device__ __forceinline__ float dpp_xor2(float x) {
    return __int_as_float(__builtin_amdgcn_mov_dpp(__float_as_int(x), 0x4E, 0xf, 0xf, true));
}

// ---------------------------------------------------------------------------
// K1 (fused): x16 convert | tgt histogram | M16t build | Zc16t build
// ---------------------------------------------------------------------------
__global__ __launch_bounds__(256) void k1_prep_kernel(const float* __restrict__ x,
                                                      __half* __restrict__ x16,
                                                      const int* __restrict__ ei,
                                                      int* __restrict__ cnt,
                                                      double* __restrict__ S,
                                                      const float* __restrict__ Wq,
                                                      const float* __restrict__ Wk,
                                                      const float* __restrict__ Wv,
                                                      const float* __restrict__ Wout,
                                                      __half* __restrict__ M16t,
                                                      __half* __restrict__ Zc16t) {
    __shared__ float sbuf[4][64];
    const int b = blockIdx.x, tid = threadIdx.x;
    if (b < NB_X16) {
        int i = b * 256 + tid;
        if (i < HEADS) S[i] = 0.0;
        int k = i * 4;
        if (k < N_NODES * IN_CH) {
            float4 v = *(const float4*)(x + k);
            union { __half2 h[2]; uint2 u; } pk;
            pk.h[0] = __floats2half2_rn(v.x, v.y);
            pk.h[1] = __floats2half2_rn(v.z, v.w);
            *(uint2*)(x16 + k) = pk.u;
        }
    } else if (b < NB_X16 + NB_HIST) {
        int e = (b - NB_X16) * 256 + tid;
        if (e < N_EDGES) atomicAdd(&cnt[ei[N_EDGES + e]], 1);
    } else if (b < NB_X16 + NB_HIST + NB_MB) {
        const int r = (b - NB_X16 - NB_HIST) * 2 + (tid >> 7);  // M-row 0..511
        const int i = tid & 127;
        const int h = r >> 7, j = r & 127;
        float* buf = sbuf[tid >> 7];
        if (i < 64) buf[i] = Wk[(size_t)j * D + h * 64 + i];
        __syncthreads();
        const float4* qr = (const float4*)(Wq + (size_t)i * D + h * 64);
        float s = 0.f;
        #pragma unroll
        for (int c4 = 0; c4 < 16; ++c4) {
            float4 q = qr[c4];
            s += q.x * buf[c4 * 4] + q.y * buf[c4 * 4 + 1]
               + q.z * buf[c4 * 4 + 2] + q.w * buf[c4 * 4 + 3];
        }
        M16t[(size_t)r * IN_CH + i] = __float2half(s);
    } else {
        const int r = (b - NB_X16 - NB_HIST - NB_MB) * 4 + (tid >> 6); // Zc-row
        const int c = tid & 63;
        const int h = r >> 7, i = r & 127;
        float* buf = sbuf[tid >> 6];
        buf[c] = Wv[(size_t)i * D + h * 64 + c];
        __syncthreads();
        float s = 0.f;
        #pragma unroll 8
        for (int j = 0; j < 64; ++j)
            s += buf[j] * Wout[(size_t)(h * 64 + j) * OUT_CH + c];
        Zc16t[(size_t)c * UDIM + r] = __float2half(s);
    }
}

// ---------------------------------------------------------------------------
// K2: scan_reduce — per-1024-chunk sums of cnt into csum (49 blocks)
// ---------------------------------------------------------------------------
__global__ __launch_bounds__(256) void k2_scan_reduce_kernel(const int* __restrict__ cnt,
                                                             int* __restrict__ csum) {
    const int b = blockIdx.x, tid = threadIdx.x;
    const int lane = tid & 63, wid = tid >> 6;
    int s = 0;
    int idx0 = b * 1024 + tid * 4;
    #pragma unroll
    for (int i = 0; i < 4; ++i) {
        int idx = idx0 + i;
        if (idx < N_NODES) s += cnt[idx];
    }
    #pragma unroll
    for (int m = 1; m < 64; m <<= 1) s += __shfl_xor(s, m, 64);
    __shared__ int w4[4];
    if (lane == 0) w4[wid] = s;
    __syncthreads();
    if (tid == 0) csum[b] = w4[0] + w4[1] + w4[2] + w4[3];
}

// ---------------------------------------------------------------------------
// K3: scan_chunks with inlined 49-element top-scan
// ---------------------------------------------------------------------------
__global__ __launch_bounds__(256) void k3_scan_chunks_kernel(int* __restrict__ cnt,
                                                             const int* __restrict__ csum,
                                                             int* __restrict__ rp) {
    __shared__ int stop[64];
    __shared__ int wsum[4];
    const int b = blockIdx.x, tid = threadIdx.x;
    const int lane = tid & 63, wid = tid >> 6;
    if (tid < 64) stop[tid] = (tid < NC) ? csum[tid] : 0;
    __syncthreads();
    int base = 0;
    for (int w = 0; w < b; ++w) base += stop[w];
    int v[4];
    const int idx0 = b * 1024 + tid * 4;
    #pragma unroll
    for (int i = 0; i < 4; ++i) {
        int idx = idx0 + i;
        v[i] = (idx < N_NODES) ? cnt[idx] : 0;
    }
    int tsum = v[0] + v[1] + v[2] + v[3];
    int x = tsum;
    #pragma unroll
    for (int d = 1; d < 64; d <<= 1) {
        int y = __shfl_up(x, d, 64);
        if (lane >= d) x += y;
    }
    if (lane == 63) wsum[wid] = x;
    __syncthreads();
    int woff = 0;
    for (int w = 0; w < wid; ++w) woff += wsum[w];
    int excl = base + woff + x - tsum;
    #pragma unroll
    for (int i = 0; i < 4; ++i) {
        int idx = idx0 + i;
        if (idx < N_NODES) { rp[idx] = excl; cnt[idx] = excl; }
        excl += v[i];
    }
}

// ---------------------------------------------------------------------------
// K4 (round-5 validated; gemm/scatter proportionally interleaved):
//   gemm blocks (1564): GEMM1 u16 = x16 @ M16t^T (128x128 tile)
//   scat blocks (1954): scatter edges -> payload {src, w} (CSR by tgt)
// A-tile direct-loaded (no LDS); B-tile staged + reused for C epilogue.
// ---------------------------------------------------------------------------
__global__ __launch_bounds__(256) void k4_gemmu_scatter_kernel(const __half* __restrict__ x16,
                                                               const __half* __restrict__ M16t,
                                                               __half* __restrict__ u16,
                                                               const int* __restrict__ ei,
                                                               const float* __restrict__ ew,
                                                               int* __restrict__ cnt,
                                                               int2* __restrict__ payload) {
    __shared__ __half Bm[128][136];   // 34,816 B; B-tile, then C staging
    const int tid = threadIdx.x;
    const int b = blockIdx.x;
    // proportional striping: exact NB_GEMM gemm slots, NB_SCAT scatter slots
    const int glo = (int)(((long long)b * NB_GEMM) / NB_K4);
    const int ghi = (int)(((long long)(b + 1) * NB_GEMM) / NB_K4);
    if (ghi == glo) {
        // ---- scatter (id = b - glo) ----
        int e = (b - glo) * 256 + tid;
        if (e < N_EDGES) {
            int s = ei[e], t = ei[N_EDGES + e];
            int pos = atomicAdd(&cnt[t], 1);
            payload[pos] = make_int2(s, __float_as_int(ew[e]));
        }
        return;
    }
    // ---- GEMM1 (id = glo) ----
    const int m0 = (glo % 391) * 128;
    const int colbase = (glo / 391) * 128;
    {
        const int r = tid >> 1, part = tid & 1;   // 64 halves = 8 uint4/thread
        const uint4* sb = (const uint4*)(M16t + (size_t)(colbase + r) * IN_CH + part * 64);
        uint4* db = (uint4*)&Bm[r][part * 64];
        #pragma unroll
        for (int q = 0; q < 8; ++q) db[q] = sb[q];
    }

    const int w = tid >> 6, lane = tid & 63;
    const int mrow = lane & 15, quad = lane >> 4;

    // A fragments: direct from x16 (each element consumed by exactly one lane)
    half8 a[2][4];
    #pragma unroll
    for (int mt = 0; mt < 2; ++mt) {
        int row = min(m0 + w * 32 + mt * 16 + mrow, N_NODES - 1); // pad rows read 49999; never stored
        const __half* ab = x16 + (size_t)row * IN_CH + quad * 8;
        #pragma unroll
        for (int ks = 0; ks < 4; ++ks) a[mt][ks] = *(const half8*)(ab + ks * 32);
    }
    __syncthreads();

    floatx4 acc[2][8];
    #pragma unroll
    for (int mt = 0; mt < 2; ++mt)
        #pragma unroll
        for (int nt = 0; nt < 8; ++nt)
            acc[mt][nt] = (floatx4){0.f, 0.f, 0.f, 0.f};

    #pragma unroll
    for (int nt = 0; nt < 8; ++nt) {
        #pragma unroll
        for (int ks = 0; ks < 4; ++ks) {
            half8 bfr = *(const half8*)&Bm[nt * 16 + mrow][ks * 32 + quad * 8];
            acc[0][nt] = __builtin_amdgcn_mfma_f32_16x16x32_f16(a[0][ks], bfr, acc[0][nt], 0, 0, 0);
            acc[1][nt] = __builtin_amdgcn_mfma_f32_16x16x32_f16(a[1][ks], bfr, acc[1][nt], 0, 0, 0);
        }
    }
    __syncthreads();   // all waves done reading Bm before overwrite
    #pragma unroll
    for (int mt = 0; mt < 2; ++mt)
        #pragma unroll
        for (int nt = 0; nt < 8; ++nt)
            #pragma unroll
            for (int r = 0; r < 4; ++r)
                Bm[w * 32 + mt * 16 + quad * 4 + r][nt * 16 + mrow] = __float2half(acc[mt][nt][r]);
    __syncthreads();
    {
        const int r = tid >> 1, part = tid & 1;
        if (m0 + r < N_NODES) {
            const uint4* s4 = (const uint4*)&Bm[r][part * 64];
            uint4* d4 = (uint4*)(u16 + (size_t)(m0 + r) * UDIM + colbase + part * 64);
            #pragma unroll
            for (int q = 0; q < 8; ++q) d4[q] = s4[q];
        }
    }
}

// ---------------------------------------------------------------------------
// Fused edge kernel v11: v10's ring + p-GEMM epilogue, with the epilogue
// made ~free: (1) LDS union — y_lds (16.6KB) and p staging (8.4KB) overlay
// the dead {xring+pbuf} region (20KB total vs v10's 36.9KB); (2) the 16 Zc
// fragments are preloaded to registers right after the loop exits so their
// L2 latency hides under the y-store/barrier/a2 sequence.
// Phases: loop -> [zc issue] -> bar -> y write -> bar -> a2 read -> bar ->
//         MFMA + p write -> bar -> coalesced store.
// ---------------------------------------------------------------------------
__global__ __launch_bounds__(256) void edge_fused_kernel(const __half* __restrict__ u16,
                                                         const __half* __restrict__ x16,
                                                         const int* __restrict__ rp,
                                                         const int* __restrict__ cnt,
                                                         const int2* __restrict__ payload,
                                                         const float* __restrict__ We,
                                                         const __half* __restrict__ Zc16t,
                                                         __half* __restrict__ p16,
                                                         double* __restrict__ S) {
    // 9984 halves = 19.97KB union:
    //   loop phase : xring = smem[0..8192)  (wave w at w*2048 + slot*512)
    //                pbuf  = (int2*)&smem[8192]  (448 int2 = 1792 halves)
    //   epi phase 1: y_lds rows r at smem[r*520 .. +512)   (max 8312)
    //   epi phase 2: p tile rows r at smem[r*264 .. +256)  (max 4216)
    __shared__ __attribute__((aligned(16))) __half smem[9984];
    __shared__ float sblk[4];
    const int tid = threadIdx.x;
    const int nodebase = blockIdx.x * 16;

    int2* pbuf = (int2*)&smem[8192];

    const int span0 = rp[nodebase];
    const int span1 = cnt[nodebase + 15];
    const int span  = span1 - span0;
    const int span_len = min(span, PCAP);
    for (int i = tid; i < span_len; i += 256) pbuf[i] = payload[span0 + i];
    if (tid < 4) sblk[tid] = 0.f;
    __syncthreads();

    const int w = tid >> 6, lane = tid & 63;
    const int g = lane >> 4;         // node-group within wave (0..3)
    const int l16 = lane & 15;
    const int h = l16 >> 2;          // head 0..3
    const int q = l16 & 3;           // channel quarter 0..3
    const int node = nodebase + (tid >> 4);
    const float wev = We[h];

    uint4 ur4[4];
    {
        const uint4* ub = (const uint4*)(u16 + (size_t)node * UDIM + h * 128 + q * 32);
        ur4[0] = ub[0]; ur4[1] = ub[1]; ur4[2] = ub[2]; ur4[3] = ub[3];
    }
    const half2_t* uh = (const half2_t*)ur4;    // 16 half2

    half2_t yacc[16];
    #pragma unroll
    for (int t = 0; t < 16; ++t) yacc[t] = (half2_t){(_Float16)0.f, (_Float16)0.f};

    float sacc = 0.f;
    const int start = rp[node];
    const int end = cnt[node];
    const int ng = end - start;

    if (span <= PCAP) {
        // ================= fast path: async ring =================
        int nmax = ng;
        nmax = max(nmax, __shfl_xor(nmax, 16, 64));
        nmax = max(nmax, __shfl_xor(nmax, 32, 64));
        if (nmax > 0) {
            // swizzled source chunk for this lane: chunk index = l16 ^ g (16B chunks)
            const int chunk_off = (l16 ^ g) * 8;   // in halves
            auto src_of = [&](int t) -> const __half* {
                int idx = min(start + t, end - 1);
                idx = max(idx, span0);             // ng==0 lanes clamp into valid span
                int s = pbuf[idx - span0].x;
                return x16 + (size_t)s * IN_CH + chunk_off;
            };
            #pragma unroll
            for (int s = 0; s < DEPTH; ++s)
                gll16(src_of(s), &smem[w * 2048 + s * 512]);

            for (int t = 0; t < nmax; ++t) {
                const int slot = t & (DEPTH - 1);
                asm volatile("s_waitcnt vmcnt(3)" ::: "memory");   // DEPTH-1
                __builtin_amdgcn_sched_barrier(0);
                // read this lane's 64B quarter (chunks q*4..q*4+3, de-swizzled)
                const uint4* rb = (const uint4*)&smem[w * 2048 + slot * 512 + g * 128 + q * 32];
                uint4 xr0 = rb[0 ^ g];
                uint4 xr1 = rb[1 ^ g];
                uint4 xr2 = rb[2 ^ g];
                uint4 xr3 = rb[3 ^ g];
                asm volatile("s_waitcnt lgkmcnt(0)" ::: "memory"); // reads done before overwrite
                __builtin_amdgcn_sched_barrier(0);
                gll16(src_of(t + DEPTH), &smem[w * 2048 + slot * 512]);  // reissue

                int2 pl;
                {
                    int idx = min(start + t, end - 1);
                    idx = max(idx, span0);
                    pl = pbuf[idx - span0];
                }
                uint4 xr[4] = {xr0, xr1, xr2, xr3};
                const half2_t* xh = (const half2_t*)xr;
                float d0 = 0.f, d1 = 0.f, d2 = 0.f, d3 = 0.f;
                #pragma unroll
                for (int tt = 0; tt < 4; ++tt) {
                    d0 = __builtin_amdgcn_fdot2(uh[tt],      xh[tt],      d0, false);
                    d1 = __builtin_amdgcn_fdot2(uh[tt + 4],  xh[tt + 4],  d1, false);
                    d2 = __builtin_amdgcn_fdot2(uh[tt + 8],  xh[tt + 8],  d2, false);
                    d3 = __builtin_amdgcn_fdot2(uh[tt + 12], xh[tt + 12], d3, false);
                }
                float dot = (d0 + d1) + (d2 + d3);
                dot += dpp_xor1(dot);
                dot += dpp_xor2(dot);            // sum over the 4 q-lanes (one aligned quad)
                float l = dot * 0.125f + __int_as_float(pl.y) * wev;
                l = fmaxf(l, 0.2f * l);          // leaky_relu(0.2)
                float p = __expf(l);
                if (t < ng) {
                    if (q == 0) sacc += p;
                    half2_t p2 = (half2_t){(_Float16)p, (_Float16)p};
                    #pragma unroll
                    for (int tt = 0; tt < 16; ++tt)
                        yacc[tt] = p2 * xh[tt] + yacc[tt];   // v_pk_fma_f16
                }
            }
        }
    } else {
        // ================= slow path (span > PCAP, ~never) =================
        auto getpl = [&](int e) -> int2 {
            int idx = e - span0;
            return (idx < PCAP) ? pbuf[idx] : payload[e];
        };
        int2 pl = make_int2(0, 0);
        uint4 xr[4];
        if (start < end) {
            pl = getpl(start);
            const uint4* xb = (const uint4*)(x16 + (size_t)pl.x * IN_CH + q * 32);
            xr[0] = xb[0]; xr[1] = xb[1]; xr[2] = xb[2]; xr[3] = xb[3];
        }
        for (int e = start; e < end; ++e) {
            int2 pln = pl;
            uint4 xrn[4] = {xr[0], xr[1], xr[2], xr[3]};
            if (e + 1 < end) {
                pln = getpl(e + 1);
                const uint4* xb = (const uint4*)(x16 + (size_t)pln.x * IN_CH + q * 32);
                xrn[0] = xb[0]; xrn[1] = xb[1]; xrn[2] = xb[2]; xrn[3] = xb[3];
            }
            const half2_t* xh = (const half2_t*)xr;
            float dot = 0.f;
            #pragma unroll
            for (int t = 0; t < 16; ++t)
                dot = __builtin_amdgcn_fdot2(uh[t], xh[t], dot, false);
            dot += __shfl_xor(dot, 1, 16);
            dot += __shfl_xor(dot, 2, 16);
            float l = dot * 0.125f + __int_as_float(pl.y) * wev;
            l = fmaxf(l, 0.2f * l);
            float p = __expf(l);
            if (q == 0) sacc += p;
            half2_t p2 = (half2_t){(_Float16)p, (_Float16)p};
            #pragma unroll
            for (int t = 0; t < 16; ++t)
                yacc[t] = p2 * xh[t] + yacc[t];
            pl = pln;
            xr[0] = xrn[0]; xr[1] = xrn[1]; xr[2] = xrn[2]; xr[3] = xrn[3];
        }
    }

    const int mrow = lane & 15, quad = lane >> 4;

    // ---- issue Zc fragment loads NOW (latency hides under next 3 phases) ----
    half8 zc[4][4];
    #pragma unroll
    for (int nt = 0; nt < 4; ++nt) {
        const __half* bb = Zc16t + (size_t)(nt * 16 + mrow) * UDIM + w * 128 + quad * 8;
        #pragma unroll
        for (int ks = 0; ks < 4; ++ks)
            zc[nt][ks] = *(const half8*)(bb + ks * 32);
    }

    __syncthreads();   // ALL waves out of loop: xring + pbuf now dead

    // ---- y -> LDS union region (rows stride 520 halves) ----
    {
        uint4* yo = (uint4*)&smem[(tid >> 4) * 520 + h * 128 + q * 32];
        const uint4* ys = (const uint4*)yacc;
        yo[0] = ys[0]; yo[1] = ys[1]; yo[2] = ys[2]; yo[3] = ys[3];
    }
    if (q == 0) atomicAdd(&sblk[h], sacc);
    __syncthreads();   // y visible + sblk complete
    if (tid < 4) atomicAdd(&S[tid], (double)sblk[tid]);

    // ---- a2 fragments from y (wave w = head w) ----
    half8 a2[4];
    #pragma unroll
    for (int ks = 0; ks < 4; ++ks)
        a2[ks] = *(const half8*)&smem[mrow * 520 + w * 128 + ks * 32 + quad * 8];
    __syncthreads();   // all a2 reads done before p overlays the region

    // ---- MFMA + p fragments -> LDS (rows stride 264), then coalesced store
    #pragma unroll
    for (int nt = 0; nt < 4; ++nt) {
        floatx4 acc = (floatx4){0.f, 0.f, 0.f, 0.f};
        #pragma unroll
        for (int ks = 0; ks < 4; ++ks)
            acc = __builtin_amdgcn_mfma_f32_16x16x32_f16(a2[ks], zc[nt][ks], acc, 0, 0, 0);
        #pragma unroll
        for (int r = 0; r < 4; ++r)
            smem[(quad * 4 + r) * 264 + w * 64 + nt * 16 + mrow] = __float2half(acc[r]);
    }
    __syncthreads();   // p tile complete
    {
        const int row = tid >> 4, part = tid & 15;   // 16 threads/row x 32B = 512B
        uint4 v0 = *(const uint4*)&smem[row * 264 + part * 16];
        uint4 v1 = *(const uint4*)&smem[row * 264 + part * 16 + 8];
        uint4* dst = (uint4*)(p16 + (size_t)(nodebase + row) * D + part * 16);
        dst[0] = v0;
        dst[1] = v1;
    }
}

// ---------------------------------------------------------------------------
// Finalize: out[n][c] = sum_h (1/S[h]) * p_h[n][c] + b_out[c].  Elementwise,
// fully coalesced.
// ---------------------------------------------------------------------------
__global__ __launch_bounds__(256) void finalize_kernel(const __half* __restrict__ p16,
                                                       const double* __restrict__ S,
                                                       const float* __restrict__ b_out,
                                                       float* __restrict__ out) {
    const int idx = blockIdx.x * 256 + threadIdx.x;   // 50000*64 exact
    const int n = idx >> 6, c = idx & 63;
    const float i0 = (float)(1.0 / S[0]);
    const float i1 = (float)(1.0 / S[1]);
    const float i2 = (float)(1.0 / S[2]);
    const float i3 = (float)(1.0 / S[3]);
    const __half* pr = p16 + (size_t)n * D + c;
    float v = __half2float(pr[0])   * i0
            + __half2float(pr[64])  * i1
            + __half2float(pr[128]) * i2
            + __half2float(pr[192]) * i3;
    out[(size_t)n * OUT_CH + c] = v + b_out[c];
}

// ---------------------------------------------------------------------------
// Launch
// ---------------------------------------------------------------------------
extern "C" void kernel_launch(void* const* d_in, const int* in_sizes, int n_in,
                              void* d_out, int out_size, void* d_ws, size_t ws_size,
                              hipStream_t stream) {
    const float* x     = (const float*)d_in[0];
    const int*   ei    = (const int*)d_in[1];   // [2, E] int32
    const float* ew    = (const float*)d_in[2];
    const float* Wq    = (const float*)d_in[3];
    const float* Wk    = (const float*)d_in[4];
    const float* Wv    = (const float*)d_in[5];
    const float* We    = (const float*)d_in[6];
    const float* Wout  = (const float*)d_in[7];
    const float* b_out = (const float*)d_in[8];
    float* out = (float*)d_out;

    // workspace layout (p16 reuses the old y16 slot; layout otherwise unchanged)
    __half* u16   = (__half*)d_ws;                          // 50000*512*2 = 51.2 MB
    __half* p16   = u16 + (size_t)N_NODES * UDIM;           // 50000*256*2 = 25.6 MB
    __half* x16   = p16 + (size_t)N_NODES * UDIM;           // 12.8 MB (offset kept)
    double* S     = (double*)(x16 + (size_t)N_NODES * IN_CH);  // 4 doubles
    __half* M16t  = (__half*)(S + HEADS);                   // 512*128*2 = 128 KB
    __half* Zc16t = M16t + UDIM * IN_CH;                    // 64*512*2 = 64 KB
    int*    rp    = (int*)(Zc16t + OUT_CH * UDIM);          // 50000
    int*    cnt   = rp + N_NODES;                           // 50000
    int*    csum  = cnt + N_NODES;                          // 64
    int2*   payload = (int2*)(csum + 64);                   // 500000*8 = 4 MB

    hipMemsetAsync(cnt, 0, N_NODES * sizeof(int), stream);
    k1_prep_kernel<<<NB_X16 + NB_HIST + NB_MB + NB_ZB, 256, 0, stream>>>(
        x, x16, ei, cnt, S, Wq, Wk, Wv, Wout, M16t, Zc16t);
    k2_scan_reduce_kernel<<<NC, 256, 0, stream>>>(cnt, csum);
    k3_scan_chunks_kernel<<<NC, 256, 0, stream>>>(cnt, csum, rp);
    k4_gemmu_scatter_kernel<<<NB_K4, 256, 0, stream>>>(
        x16, M16t, u16, ei, ew, cnt, payload);
    edge_fused_kernel<<<N_NODES / 16, 256, 0, stream>>>(
        u16, x16, rp, cnt, payload, We, Zc16t, p16, S);
    finalize_kernel<<<(N_NODES * OUT_CH) / 256, 256, 0, stream>>>(p16, S, b_out, out);
}